// Round 1
// baseline (1274.855 us; speedup 1.0000x reference)
//
#include <hip/hip_runtime.h>
#include <stdint.h>

// RotEncoderMLP via Z4-spectral (DFT) decomposition of the C4 group convs.
//   x^[0]=x0+x1+x2+x3, x^[2]=x0-x1+x2-x3, x^[1]=ur+i*ui (ur=x0-x2, ui=x3-x1)
//   y^[w] = conj(W^[w]) . x^[w];  y[g] = (1/4)[y^0 + (-1)^g y^2 + 2 Re(y^1 i^g)]
// MACs: 16*HID^2 -> 6*HID^2.
// R7: GEMM rebuilt as 256x256 8-phase pipelined schedule (T2+T3+T4+T5 per the
// verified m201 template): 512 thr / 8 waves (2Mx4N), BK=64, 128 KiB LDS double
// buffer, one half-tile staged per phase, counted s_waitcnt vmcnt(6) at phases
// 4/8 only (no vmcnt(0) drain in the K-loop), raw s_barrier, setprio around the
// 16-MFMA clusters. LDS rows remapped so A mh-strips / B nh-stripes are
// contiguous 64-row global_load_lds sweeps; XOR swizzle (chunk ^= row&7, source
// pre-swizzled) kept -> 0 bank conflicts. XCD-chunked panel-major traversal.

#define HID 2048
#define MROWS 10240

typedef float floatx4 __attribute__((ext_vector_type(4)));
typedef __bf16 bf16x8 __attribute__((ext_vector_type(8)));

__device__ __forceinline__ unsigned short f2bf(float f) {
  union { float f; unsigned int u; } v; v.f = f;
  unsigned int r = v.u + 0x7fffu + ((v.u >> 16) & 1u);  // RNE
  return (unsigned short)(r >> 16);
}
__device__ __forceinline__ float bf2f(unsigned short s) {
  union { unsigned int u; float f; } v; v.u = ((unsigned int)s) << 16;
  return v.f;
}

// ---------- spectral weight transform: w (4,NO,2048) f32 -> W0s, W2s (NO x 2048 bf16),
// Bc (2*NO x 4096 bf16) = [[Vr, -Vi],[Vi, Vr]] ----------
template <int NO>
__global__ __launch_bounds__(256) void wtrans_kernel(const float* __restrict__ w,
                                                     unsigned short* __restrict__ W0s,
                                                     unsigned short* __restrict__ W2s,
                                                     unsigned short* __restrict__ Bc) {
  int idx = blockIdx.x * 256 + threadIdx.x;       // i * 512 + j4
  int i = idx >> 9, j4 = idx & 511;
  const float4* wp = (const float4*)w;
  float4 w0 = wp[0 * NO * 512 + i * 512 + j4];
  float4 w1 = wp[1 * NO * 512 + i * 512 + j4];
  float4 w2 = wp[2 * NO * 512 + i * 512 + j4];
  float4 w3 = wp[3 * NO * 512 + i * 512 + j4];
  ushort4 s0, s2, vr, vi, nvi;
#define DO(c)                                        \
  s0.c = f2bf(w0.c + w1.c + w2.c + w3.c);            \
  s2.c = f2bf(w0.c - w1.c + w2.c - w3.c);            \
  vr.c = f2bf(w0.c - w2.c);                          \
  vi.c = f2bf(w1.c - w3.c);                          \
  nvi.c = f2bf(-(w1.c - w3.c));
  DO(x) DO(y) DO(z) DO(w)
#undef DO
  ((ushort4*)W0s)[i * 512 + j4] = s0;
  ((ushort4*)W2s)[i * 512 + j4] = s2;
  ((ushort4*)Bc)[i * 1024 + j4] = vr;            // row i:    [Vr | -Vi]
  ((ushort4*)Bc)[i * 1024 + 512 + j4] = nvi;
  ((ushort4*)Bc)[(NO + i) * 1024 + j4] = vi;     // row NO+i: [Vi |  Vr]
  ((ushort4*)Bc)[(NO + i) * 1024 + 512 + j4] = vr;
}

// ---------- orbit-stack + layer1 + relu + forward-DFT -> h1s bf16 (Mc x 8192: [u0|u2|ur|ui]) ----------
__global__ __launch_bounds__(256) void layer1_kernel(const float* __restrict__ ins,
                                                     const float* __restrict__ w1,
                                                     const float* __restrict__ b1,
                                                     unsigned short* __restrict__ h1s,
                                                     int row0) {
  __shared__ float orbs[32][28];
  int t = threadIdx.x;
  int b0 = blockIdx.x * 32;            // chunk-local
  int i = blockIdx.y * 256 + t;
  if (t < 32) {
    const float* x = ins + (size_t)(row0 + b0 + t) * 25;
    float v[25];
#pragma unroll
    for (int p = 0; p < 25; ++p) v[p] = x[p];
    float* o = orbs[t];
    o[0] = v[12]; o[7] = v[12]; o[14] = v[12]; o[21] = v[12];
#pragma unroll
    for (int r = 0; r < 2; ++r)
#pragma unroll
      for (int c = 0; c < 3; ++c) {
        int m = 1 + r * 3 + c;
        o[m]      = v[r * 5 + c];
        o[7 + m]  = v[c * 5 + (4 - r)];
        o[14 + m] = v[(4 - r) * 5 + (4 - c)];
        o[21 + m] = v[(4 - c) * 5 + r];
      }
  }
  __syncthreads();
  float w[4][7];
#pragma unroll
  for (int r = 0; r < 4; ++r)
#pragma unroll
    for (int j = 0; j < 7; ++j) w[r][j] = w1[(r * HID + i) * 7 + j];
  float bias = b1[i];
  for (int s = 0; s < 32; ++s) {
    float a[4] = {bias, bias, bias, bias};
#pragma unroll
    for (int hh = 0; hh < 4; ++hh)
#pragma unroll
      for (int j = 0; j < 7; ++j) {
        float ov = orbs[s][hh * 7 + j];
#pragma unroll
        for (int g = 0; g < 4; ++g) a[g] += w[(hh - g) & 3][j] * ov;
      }
    float h0 = fmaxf(a[0], 0.f), h1 = fmaxf(a[1], 0.f);
    float h2 = fmaxf(a[2], 0.f), h3 = fmaxf(a[3], 0.f);
    size_t base = (size_t)(b0 + s) * 8192 + i;
    h1s[base]        = f2bf(h0 + h1 + h2 + h3);  // u0
    h1s[base + 2048] = f2bf(h0 - h1 + h2 - h3);  // u2
    h1s[base + 4096] = f2bf(h0 - h2);            // ur
    h1s[base + 6144] = f2bf(h3 - h1);            // ui
  }
}

// ---------- 256x256 8-phase pipelined bf16 MFMA GEMM, 3 spectral segments ----------
// n-tile nt routing: nt<s1: B0,K=2048,aoff=0; nt<s2: B1,K=2048,aoff=2048; else B2,K=4096,aoff=4096.
// Output: bf16 to Cb (if non-null) else f32 to Cf.
#define PW 4  // panel width in n-tiles

// LDS row remap (so each half-tile is 2 contiguous 64-row sweeps):
//   A: lrow = mh*128 + (r>>7)*64 + (r&63), mh=(r>>6)&1  (mh-strips contiguous)
//   B: lrow = nh*128 + (r>>6)*32 + (r&31), nh=(r>>5)&1  (nh-stripes contiguous)
// Chunk swizzle: LDS (lrow, ch) holds global k-chunk ch ^ (lrow&7); staged by
// pre-swizzling the global source column; read with ch = c ^ (lane15&7).

__global__ __launch_bounds__(512, 2) void gemm_spec(const unsigned short* __restrict__ A,
                                                    const unsigned short* __restrict__ B0,
                                                    const unsigned short* __restrict__ B1,
                                                    const unsigned short* __restrict__ B2,
                                                    float* __restrict__ Cf,
                                                    unsigned short* __restrict__ Cb,
                                                    int s1, int s2, int N0, int ldc) {
  __shared__ __align__(16) unsigned short As[2][16384];
  __shared__ __align__(16) unsigned short Bs[2][16384];
  int tid = threadIdx.x;
  int wave = tid >> 6, lane = tid & 63;
  int lane15 = lane & 15, lane4 = lane >> 4, l7 = lane15 & 7;
  int wm = wave >> 2, wn = wave & 3;
  int wm64 = wm << 6, wn32 = wn << 5;

  // XCD-chunked, panel-major traversal (nwg % 8 == 0 in all launch configs)
  int nwg = gridDim.x * gridDim.y;
  int q8 = nwg >> 3;
  int flat = blockIdx.y * gridDim.x + blockIdx.x;
  int swz = (flat & 7) * q8 + (flat >> 3);
  int pgy = PW * gridDim.y;
  int panel = swz / pgy, rem = swz % pgy;
  int mt = rem / PW;
  int nt = panel * PW + (rem % PW);
  int m0 = mt * 256;

  const unsigned short* Bp;
  int K, aoff, coff, nloc;
  if (nt < s1)      { Bp = B0; K = 2048; aoff = 0;    coff = 0;      nloc = nt * 256; }
  else if (nt < s2) { Bp = B1; K = 2048; aoff = 2048; coff = N0;     nloc = (nt - s1) * 256; }
  else              { Bp = B2; K = 4096; aoff = 4096; coff = 2 * N0; nloc = (nt - s2) * 256; }
  int ldb = K;

  int srow = tid >> 3;                               // 0..63 within a sweep
  int scol = ((tid & 7) ^ ((tid >> 3) & 7)) << 3;    // pre-swizzled source chunk
  const unsigned short* Agb = A + (size_t)(m0 + srow) * 8192 + aoff + scol;
  const unsigned short* Bgb = Bp + (size_t)(nloc + (srow & 31)) * ldb + scol;
  int bs64 = (srow >> 5) << 6;                       // 0 or 64 (wave-uniform)

#define STA(buf, mh, kk)                                                                              \
  __builtin_amdgcn_global_load_lds(                                                                   \
      (const __attribute__((address_space(1))) void*)(Agb + (size_t)((mh) * 64) * 8192 + (kk)),       \
      (__attribute__((address_space(3))) void*)((char*)As[buf] + (mh) * 16384 + wave * 1024),         \
      16, 0, 0);                                                                                      \
  __builtin_amdgcn_global_load_lds(                                                                   \
      (const __attribute__((address_space(1))) void*)(Agb + (size_t)((mh) * 64 + 128) * 8192 + (kk)), \
      (__attribute__((address_space(3))) void*)((char*)As[buf] + (mh) * 16384 + 8192 + wave * 1024),  \
      16, 0, 0)

#define STB(buf, nh, kk)                                                                              \
  __builtin_amdgcn_global_load_lds(                                                                   \
      (const __attribute__((address_space(1))) void*)(Bgb + (size_t)(bs64 + (nh) * 32) * ldb + (kk)), \
      (__attribute__((address_space(3))) void*)((char*)Bs[buf] + (nh) * 16384 + wave * 1024),         \
      16, 0, 0);                                                                                      \
  __builtin_amdgcn_global_load_lds(                                                                   \
      (const __attribute__((address_space(1))) void*)(Bgb + (size_t)(bs64 + 128 + (nh) * 32) * ldb + (kk)), \
      (__attribute__((address_space(3))) void*)((char*)Bs[buf] + (nh) * 16384 + 8192 + wave * 1024),  \
      16, 0, 0)

#define RAF(buf, mh)                                                                                  \
  _Pragma("unroll") for (int mi_ = 0; mi_ < 4; ++mi_)                                                 \
  _Pragma("unroll") for (int ks_ = 0; ks_ < 2; ++ks_)                                                 \
      af[mi_][ks_] = *(const bf16x8*)((const char*)As[buf] +                                          \
          (((mh) * 128 + wm64 + mi_ * 16 + lane15) << 7) + (((ks_ * 4 + lane4) ^ l7) << 4))

#define RBF(dst, buf, nh)                                                                             \
  _Pragma("unroll") for (int ni_ = 0; ni_ < 2; ++ni_)                                                 \
  _Pragma("unroll") for (int ks_ = 0; ks_ < 2; ++ks_)                                                 \
      dst[ni_][ks_] = *(const bf16x8*)((const char*)Bs[buf] +                                         \
          (((nh) * 128 + wn32 + ni_ * 16 + lane15) << 7) + (((ks_ * 4 + lane4) ^ l7) << 4))

#define MM(mh, nh, bF)                                                                                \
  _Pragma("unroll") for (int mi_ = 0; mi_ < 4; ++mi_)                                                 \
  _Pragma("unroll") for (int ni_ = 0; ni_ < 2; ++ni_)                                                 \
  _Pragma("unroll") for (int ks_ = 0; ks_ < 2; ++ks_)                                                 \
      acc[(mh) * 4 + mi_][(nh) * 2 + ni_] = __builtin_amdgcn_mfma_f32_16x16x32_bf16(                  \
          af[mi_][ks_], bF[ni_][ks_], acc[(mh) * 4 + mi_][(nh) * 2 + ni_], 0, 0, 0)

#define BAR() __builtin_amdgcn_s_barrier()
#define LGKM0() asm volatile("s_waitcnt lgkmcnt(0)" ::: "memory")
#define VM6() asm volatile("s_waitcnt vmcnt(6)" ::: "memory")

  bf16x8 af[4][2], b0r[2][2], b1r[2][2];
  const floatx4 fz = {0.f, 0.f, 0.f, 0.f};
  floatx4 acc[8][4];
#pragma unroll
  for (int a = 0; a < 8; ++a)
#pragma unroll
    for (int b = 0; b < 4; ++b) acc[a][b] = fz;

  // Prologue: T0 (buf0,k=0) fully; T1 (buf1,k=64) minus A-mh1 (= 7 half-tiles,
  // 14 loads). vmcnt(6) -> T0's 8 loads landed.
  STA(0, 0, 0); STB(0, 0, 0); STB(0, 1, 0); STA(0, 1, 0);
  STA(1, 0, 64); STB(1, 0, 64); STB(1, 1, 64);
  VM6();
  BAR();

  for (int k0 = 0; k0 < K; k0 += 128) {
    // ---- P1: quad(0,0) of tile A (buf0); stage Tb.A-mh1 (buf1, freed prev P7)
    RAF(0, 0); RBF(b0r, 0, 0);
    STA(1, 1, k0 + 64);
    BAR(); LGKM0();
    __builtin_amdgcn_s_setprio(1); MM(0, 0, b0r); __builtin_amdgcn_s_setprio(0);
    BAR();
    // ---- P2: quad(0,1); stage Ta'.A-mh0 (buf0, freed P1)
    RBF(b1r, 0, 1);
    STA(0, 0, k0 + 128);
    BAR(); LGKM0();
    __builtin_amdgcn_s_setprio(1); MM(0, 1, b1r); __builtin_amdgcn_s_setprio(0);
    BAR();
    // ---- P3: quad(1,0); stage Ta'.B-nh0 (freed P1)
    RAF(0, 1);
    STB(0, 0, k0 + 128);
    BAR(); LGKM0();
    __builtin_amdgcn_s_setprio(1); MM(1, 0, b0r); __builtin_amdgcn_s_setprio(0);
    BAR();
    // ---- P4: quad(1,1); stage Ta'.B-nh1 (freed P2); counted vmcnt
    STB(0, 1, k0 + 128);
    BAR(); LGKM0();
    __builtin_amdgcn_s_setprio(1); MM(1, 1, b1r); __builtin_amdgcn_s_setprio(0);
    VM6();
    BAR();
    // ---- P5: tile B (buf1) quad(0,0); stage Ta'.A-mh1 (freed P3)
    RAF(1, 0); RBF(b0r, 1, 0);
    STA(0, 1, k0 + 128);
    BAR(); LGKM0();
    __builtin_amdgcn_s_setprio(1); MM(0, 0, b0r); __builtin_amdgcn_s_setprio(0);
    BAR();
    // ---- P6: quad(0,1); stage Tb'.A-mh0 (buf1, freed P5)
    RBF(b1r, 1, 1);
    STA(1, 0, k0 + 192);
    BAR(); LGKM0();
    __builtin_amdgcn_s_setprio(1); MM(0, 1, b1r); __builtin_amdgcn_s_setprio(0);
    BAR();
    // ---- P7: quad(1,0); stage Tb'.B-nh0 (freed P5)
    RAF(1, 1);
    STB(1, 0, k0 + 192);
    BAR(); LGKM0();
    __builtin_amdgcn_s_setprio(1); MM(1, 0, b0r); __builtin_amdgcn_s_setprio(0);
    BAR();
    // ---- P8: quad(1,1); stage Tb'.B-nh1 (freed P6); counted vmcnt
    STB(1, 1, k0 + 192);
    BAR(); LGKM0();
    __builtin_amdgcn_s_setprio(1); MM(1, 1, b1r); __builtin_amdgcn_s_setprio(0);
    VM6();
    BAR();
  }
  asm volatile("s_waitcnt vmcnt(0)" ::: "memory");

  // epilogue: C/D layout col=lane&15, row=(lane>>4)*4+r
#pragma unroll
  for (int ni = 0; ni < 4; ++ni) {
    int col = coff + nloc + wn * 64 + (ni >> 1) * 32 + (ni & 1) * 16 + lane15;
#pragma unroll
    for (int mi = 0; mi < 8; ++mi) {
      int row = m0 + wm * 128 + (mi >> 2) * 64 + (mi & 3) * 16 + lane4 * 4;
      if (Cb) {
#pragma unroll
        for (int r = 0; r < 4; ++r)
          Cb[(size_t)(row + r) * ldc + col] = f2bf(acc[mi][ni][r]);
      } else {
#pragma unroll
        for (int r = 0; r < 4; ++r)
          Cf[(size_t)(row + r) * ldc + col] = acc[mi][ni][r];
      }
    }
  }
#undef STA
#undef STB
#undef RAF
#undef RBF
#undef MM
#undef BAR
#undef LGKM0
#undef VM6
}

// ---------- inverse-DFT (+b2, /4) -> 4x LayerNorm -> relu -> forward-DFT -> h1s bf16 ----------
__global__ __launch_bounds__(256) void ln_spec_kernel(const unsigned short* __restrict__ C2,
                                                      const float* __restrict__ b2,
                                                      const float* __restrict__ ln_g,
                                                      const float* __restrict__ ln_b,
                                                      unsigned short* __restrict__ h1s) {
  int t = threadIdx.x;
  size_t base = (size_t)blockIdx.x * 8192;
  const ushort4* p = (const ushort4*)(C2 + base);   // planes: v0|v2|vr|vi (512 ushort4 each)
  const float4* bp2 = (const float4*)b2;
  float4 y[4][2];
  float s[4] = {0, 0, 0, 0}, q[4] = {0, 0, 0, 0};
#pragma unroll
  for (int hl = 0; hl < 2; ++hl) {
    int j = hl * 256 + t;
    ushort4 u0 = p[j], u2 = p[512 + j], ur = p[1024 + j], ui = p[1536 + j];
    float4 bb = bp2[j];
#define DO(c)                                                   \
  {                                                             \
    float v0 = bf2f(u0.c), v2 = bf2f(u2.c);                     \
    float vr = bf2f(ur.c), vi = bf2f(ui.c);                     \
    float e0 = 0.25f * (v0 + v2 + 2.f * vr) + bb.c;             \
    float e1 = 0.25f * (v0 - v2 - 2.f * vi) + bb.c;             \
    float e2 = 0.25f * (v0 + v2 - 2.f * vr) + bb.c;             \
    float e3 = 0.25f * (v0 - v2 + 2.f * vi) + bb.c;             \
    y[0][hl].c = e0; y[1][hl].c = e1; y[2][hl].c = e2; y[3][hl].c = e3; \
    s[0] += e0; q[0] += e0 * e0; s[1] += e1; q[1] += e1 * e1;   \
    s[2] += e2; q[2] += e2 * e2; s[3] += e3; q[3] += e3 * e3;   \
  }
    DO(x) DO(y) DO(z) DO(w)
#undef DO
  }
#pragma unroll
  for (int off = 32; off > 0; off >>= 1)
#pragma unroll
    for (int g = 0; g < 4; ++g) {
      s[g] += __shfl_down(s[g], off, 64);
      q[g] += __shfl_down(q[g], off, 64);
    }
  __shared__ float rs[4][4], rq[4][4];
  int w = t >> 6, l = t & 63;
  if (l == 0)
#pragma unroll
    for (int g = 0; g < 4; ++g) { rs[w][g] = s[g]; rq[w][g] = q[g]; }
  __syncthreads();
  float mean[4], rstd[4];
#pragma unroll
  for (int g = 0; g < 4; ++g) {
    float ss = rs[0][g] + rs[1][g] + rs[2][g] + rs[3][g];
    float qq = rq[0][g] + rq[1][g] + rq[2][g] + rq[3][g];
    mean[g] = ss * (1.f / HID);
    float var = qq * (1.f / HID) - mean[g] * mean[g];
    rstd[g] = rsqrtf(var + 1e-5f);
  }
  const float4* gp = (const float4*)ln_g;
  const float4* lbp = (const float4*)ln_b;
#pragma unroll
  for (int hl = 0; hl < 2; ++hl) {
    int j = hl * 256 + t;
    float4 gg = gp[j], lb = lbp[j];
    ushort4 o[4];
#define DO(c)                                                               \
  {                                                                         \
    float h0 = fmaxf((y[0][hl].c - mean[0]) * rstd[0] * gg.c + lb.c, 0.f);  \
    float h1 = fmaxf((y[1][hl].c - mean[1]) * rstd[1] * gg.c + lb.c, 0.f);  \
    float h2 = fmaxf((y[2][hl].c - mean[2]) * rstd[2] * gg.c + lb.c, 0.f);  \
    float h3 = fmaxf((y[3][hl].c - mean[3]) * rstd[3] * gg.c + lb.c, 0.f);  \
    o[0].c = f2bf(h0 + h1 + h2 + h3);                                       \
    o[1].c = f2bf(h0 - h1 + h2 - h3);                                       \
    o[2].c = f2bf(h0 - h2);                                                 \
    o[3].c = f2bf(h3 - h1);                                                 \
  }
    DO(x) DO(y) DO(z) DO(w)
#undef DO
    size_t ob = (size_t)blockIdx.x * 8192;
#pragma unroll
    for (int pl = 0; pl < 4; ++pl)
      ((ushort4*)(h1s + ob + pl * 2048))[j] = o[pl];
  }
}

// ---------- final inverse-DFT (+b3, /4): Z (Mc x 2048 f32 [z0|z2|zr|zi]) -> out ----------
__global__ __launch_bounds__(256) void out_ep_kernel(const float* __restrict__ Z,
                                                     const float* __restrict__ b3,
                                                     float* __restrict__ out) {
  int e = blockIdx.x * 256 + threadIdx.x;
  int row = e >> 9, i = e & 511;
  size_t base = (size_t)row * 2048;
  float z0 = Z[base + i], z2 = Z[base + 512 + i];
  float zr = Z[base + 1024 + i], zi = Z[base + 1536 + i];
  float bv = b3[i];
  out[base + i]        = 0.25f * (z0 + z2 + 2.f * zr) + bv;
  out[base + 512 + i]  = 0.25f * (z0 - z2 - 2.f * zi) + bv;
  out[base + 1024 + i] = 0.25f * (z0 + z2 - 2.f * zr) + bv;
  out[base + 1536 + i] = 0.25f * (z0 - z2 + 2.f * zi) + bv;
}

extern "C" void kernel_launch(void* const* d_in, const int* in_sizes, int n_in,
                              void* d_out, int out_size, void* d_ws, size_t ws_size,
                              hipStream_t stream) {
  const float* ins = (const float*)d_in[0];
  const float* w1  = (const float*)d_in[1];
  const float* b1  = (const float*)d_in[2];
  const float* w2  = (const float*)d_in[3];
  const float* b2  = (const float*)d_in[4];
  const float* w3  = (const float*)d_in[5];
  const float* b3  = (const float*)d_in[6];
  const float* lng = (const float*)d_in[7];
  const float* lnb = (const float*)d_in[8];
  float* out = (float*)d_out;
  char* ws = (char*)d_ws;

  // Spectral weights (bf16), persistent at base of ws.
  unsigned short* W0s2 = (unsigned short*)ws;
  unsigned short* W2s2 = W0s2 + 4194304;
  unsigned short* Bc2  = W2s2 + 4194304;
  unsigned short* W0s3 = Bc2 + 16777216;
  unsigned short* W2s3 = W0s3 + 1048576;
  unsigned short* Bc3  = W2s3 + 1048576;
  const size_t WT_BYTES = 62914560ull;
  char* chunk_base = ws + WT_BYTES;

  // Per chunk: h1s bf16 Mc*8192 + C2 bf16 Mc*8192 (Z f32 Mc*2048 aliases C2).
  // Mc must be a multiple of 256 (256x256 GEMM tiles).
  static const int Pcand[8] = {1, 2, 4, 5, 8, 10, 20, 40};
  int P = 40;
  for (int pi = 0; pi < 8; ++pi) {
    size_t mc = (size_t)MROWS / Pcand[pi];
    size_t need = WT_BYTES + mc * 8192 * 2 * 2 + 256;
    if (need <= ws_size) { P = Pcand[pi]; break; }
  }
  const int Mc = MROWS / P;
  unsigned short* h1s = (unsigned short*)chunk_base;                     // Mc x 8192 bf16
  unsigned short* C2  = (unsigned short*)(chunk_base + (size_t)Mc * 8192 * 2);
  float*          Z   = (float*)C2;                                      // Mc x 2048 f32 (alias)

  wtrans_kernel<2048><<<4096, 256, 0, stream>>>(w2, W0s2, W2s2, Bc2);
  wtrans_kernel<512><<<1024, 256, 0, stream>>>(w3, W0s3, W2s3, Bc3);

  for (int c = 0; c < P; ++c) {
    int row0 = c * Mc;
    layer1_kernel<<<dim3(Mc / 32, 8), 256, 0, stream>>>(ins, w1, b1, h1s, row0);
    // L2 spectral: n-tiles [0,8)=V0 (K=2048), [8,16)=V2, [16,32)=Bc (K=4096); bf16 out
    gemm_spec<<<dim3(32, Mc / 256), 512, 0, stream>>>(h1s, W0s2, W2s2, Bc2, nullptr, C2,
                                                      8, 16, 2048, 8192);
    ln_spec_kernel<<<Mc, 256, 0, stream>>>(C2, b2, lng, lnb, h1s);
    // L3 spectral: n-tiles [0,2)=V0', [2,4)=V2', [4,8)=Bc' -> Z f32 (ldc 2048)
    gemm_spec<<<dim3(8, Mc / 256), 512, 0, stream>>>(h1s, W0s3, W2s3, Bc3, Z, nullptr,
                                                     2, 4, 512, 2048);
    out_ep_kernel<<<Mc * 2, 256, 0, stream>>>(Z, b3, out + (size_t)row0 * 2048);
  }
}

// Round 2
// 1229.989 us; speedup vs baseline: 1.0365x; 1.0365x over previous
//
#include <hip/hip_runtime.h>
#include <stdint.h>

// RotEncoderMLP via Z4-spectral (DFT) decomposition of the C4 group convs.
//   x^[0]=x0+x1+x2+x3, x^[2]=x0-x1+x2-x3, x^[1]=ur+i*ui (ur=x0-x2, ui=x3-x1)
//   y^[w] = conj(W^[w]) . x^[w];  y[g] = (1/4)[y^0 + (-1)^g y^2 + 2 Re(y^1 i^g)]
// MACs: 16*HID^2 -> 6*HID^2.
// R7: 256x256 8-phase pipelined GEMM (m201 template: T2+T3+T4+T5).
// R8: fix XCD load imbalance found in R7 counters (occupancy 14%, makespan 1.8x
// work-depth): panels were K-homogeneous AND coincided exactly with XCD chunks
// (q8 == pgy == 80), so XCDs 0-3 got only K=2048 tiles and XCDs 4-7 only K=4096.
// Remap each panel of PW=4 n-tiles to {2 long-K first, 2 short-K} -> every XCD
// chunk balanced, LPT tail. Plus m201's optional lgkmcnt(8) pre-barrier drain in
// the 12-ds_read phases (P1/P5).

#define HID 2048
#define MROWS 10240

typedef float floatx4 __attribute__((ext_vector_type(4)));
typedef __bf16 bf16x8 __attribute__((ext_vector_type(8)));

__device__ __forceinline__ unsigned short f2bf(float f) {
  union { float f; unsigned int u; } v; v.f = f;
  unsigned int r = v.u + 0x7fffu + ((v.u >> 16) & 1u);  // RNE
  return (unsigned short)(r >> 16);
}
__device__ __forceinline__ float bf2f(unsigned short s) {
  union { unsigned int u; float f; } v; v.u = ((unsigned int)s) << 16;
  return v.f;
}

// ---------- spectral weight transform: w (4,NO,2048) f32 -> W0s, W2s (NO x 2048 bf16),
// Bc (2*NO x 4096 bf16) = [[Vr, -Vi],[Vi, Vr]] ----------
template <int NO>
__global__ __launch_bounds__(256) void wtrans_kernel(const float* __restrict__ w,
                                                     unsigned short* __restrict__ W0s,
                                                     unsigned short* __restrict__ W2s,
                                                     unsigned short* __restrict__ Bc) {
  int idx = blockIdx.x * 256 + threadIdx.x;       // i * 512 + j4
  int i = idx >> 9, j4 = idx & 511;
  const float4* wp = (const float4*)w;
  float4 w0 = wp[0 * NO * 512 + i * 512 + j4];
  float4 w1 = wp[1 * NO * 512 + i * 512 + j4];
  float4 w2 = wp[2 * NO * 512 + i * 512 + j4];
  float4 w3 = wp[3 * NO * 512 + i * 512 + j4];
  ushort4 s0, s2, vr, vi, nvi;
#define DO(c)                                        \
  s0.c = f2bf(w0.c + w1.c + w2.c + w3.c);            \
  s2.c = f2bf(w0.c - w1.c + w2.c - w3.c);            \
  vr.c = f2bf(w0.c - w2.c);                          \
  vi.c = f2bf(w1.c - w3.c);                          \
  nvi.c = f2bf(-(w1.c - w3.c));
  DO(x) DO(y) DO(z) DO(w)
#undef DO
  ((ushort4*)W0s)[i * 512 + j4] = s0;
  ((ushort4*)W2s)[i * 512 + j4] = s2;
  ((ushort4*)Bc)[i * 1024 + j4] = vr;            // row i:    [Vr | -Vi]
  ((ushort4*)Bc)[i * 1024 + 512 + j4] = nvi;
  ((ushort4*)Bc)[(NO + i) * 1024 + j4] = vi;     // row NO+i: [Vi |  Vr]
  ((ushort4*)Bc)[(NO + i) * 1024 + 512 + j4] = vr;
}

// ---------- orbit-stack + layer1 + relu + forward-DFT -> h1s bf16 (Mc x 8192: [u0|u2|ur|ui]) ----------
__global__ __launch_bounds__(256) void layer1_kernel(const float* __restrict__ ins,
                                                     const float* __restrict__ w1,
                                                     const float* __restrict__ b1,
                                                     unsigned short* __restrict__ h1s,
                                                     int row0) {
  __shared__ float orbs[32][28];
  int t = threadIdx.x;
  int b0 = blockIdx.x * 32;            // chunk-local
  int i = blockIdx.y * 256 + t;
  if (t < 32) {
    const float* x = ins + (size_t)(row0 + b0 + t) * 25;
    float v[25];
#pragma unroll
    for (int p = 0; p < 25; ++p) v[p] = x[p];
    float* o = orbs[t];
    o[0] = v[12]; o[7] = v[12]; o[14] = v[12]; o[21] = v[12];
#pragma unroll
    for (int r = 0; r < 2; ++r)
#pragma unroll
      for (int c = 0; c < 3; ++c) {
        int m = 1 + r * 3 + c;
        o[m]      = v[r * 5 + c];
        o[7 + m]  = v[c * 5 + (4 - r)];
        o[14 + m] = v[(4 - r) * 5 + (4 - c)];
        o[21 + m] = v[(4 - c) * 5 + r];
      }
  }
  __syncthreads();
  float w[4][7];
#pragma unroll
  for (int r = 0; r < 4; ++r)
#pragma unroll
    for (int j = 0; j < 7; ++j) w[r][j] = w1[(r * HID + i) * 7 + j];
  float bias = b1[i];
  for (int s = 0; s < 32; ++s) {
    float a[4] = {bias, bias, bias, bias};
#pragma unroll
    for (int hh = 0; hh < 4; ++hh)
#pragma unroll
      for (int j = 0; j < 7; ++j) {
        float ov = orbs[s][hh * 7 + j];
#pragma unroll
        for (int g = 0; g < 4; ++g) a[g] += w[(hh - g) & 3][j] * ov;
      }
    float h0 = fmaxf(a[0], 0.f), h1 = fmaxf(a[1], 0.f);
    float h2 = fmaxf(a[2], 0.f), h3 = fmaxf(a[3], 0.f);
    size_t base = (size_t)(b0 + s) * 8192 + i;
    h1s[base]        = f2bf(h0 + h1 + h2 + h3);  // u0
    h1s[base + 2048] = f2bf(h0 - h1 + h2 - h3);  // u2
    h1s[base + 4096] = f2bf(h0 - h2);            // ur
    h1s[base + 6144] = f2bf(h3 - h1);            // ui
  }
}

// ---------- 256x256 8-phase pipelined bf16 MFMA GEMM, 3 spectral segments ----------
// n-tile nt routing: nt<s1: B0,K=2048,aoff=0; nt<s2: B1,K=2048,aoff=2048; else B2,K=4096,aoff=4096.
// Work-tile -> n-tile remap for XCD balance: panel p of PW=4 work slots covers
// {nhalf+2p, nhalf+2p+1 (long K), 2p, 2p+1 (short K)} in that (LPT) order.
// Output: bf16 to Cb (if non-null) else f32 to Cf.
#define PW 4  // panel width in n-tiles

// LDS row remap (so each half-tile is 2 contiguous 64-row sweeps):
//   A: lrow = mh*128 + (r>>7)*64 + (r&63), mh=(r>>6)&1  (mh-strips contiguous)
//   B: lrow = nh*128 + (r>>6)*32 + (r&31), nh=(r>>5)&1  (nh-stripes contiguous)
// Chunk swizzle: LDS (lrow, ch) holds global k-chunk ch ^ (lrow&7); staged by
// pre-swizzling the global source column; read with ch = c ^ (lane15&7).

__global__ __launch_bounds__(512, 2) void gemm_spec(const unsigned short* __restrict__ A,
                                                    const unsigned short* __restrict__ B0,
                                                    const unsigned short* __restrict__ B1,
                                                    const unsigned short* __restrict__ B2,
                                                    float* __restrict__ Cf,
                                                    unsigned short* __restrict__ Cb,
                                                    int s1, int s2, int nhalf, int N0, int ldc) {
  __shared__ __align__(16) unsigned short As[2][16384];
  __shared__ __align__(16) unsigned short Bs[2][16384];
  int tid = threadIdx.x;
  int wave = tid >> 6, lane = tid & 63;
  int lane15 = lane & 15, lane4 = lane >> 4, l7 = lane15 & 7;
  int wm = wave >> 2, wn = wave & 3;
  int wm64 = wm << 6, wn32 = wn << 5;

  // XCD-chunked, panel-major traversal (nwg % 8 == 0 in all launch configs)
  int nwg = gridDim.x * gridDim.y;
  int q8 = nwg >> 3;
  int flat = blockIdx.y * gridDim.x + blockIdx.x;
  int swz = (flat & 7) * q8 + (flat >> 3);
  int pgy = PW * gridDim.y;
  int panel = swz / pgy, rem = swz % pgy;
  int mt = rem / PW;
  int wnt = panel * PW + (rem % PW);     // work-tile id
  // balance remap: slots 0,1 -> long-K tiles of this panel; slots 2,3 -> short-K
  int pp = wnt >> 2, pj = wnt & 3;
  int nt = (pj < 2) ? (nhalf + 2 * pp + pj) : (2 * pp + (pj - 2));
  int m0 = mt * 256;

  const unsigned short* Bp;
  int K, aoff, coff, nloc;
  if (nt < s1)      { Bp = B0; K = 2048; aoff = 0;    coff = 0;      nloc = nt * 256; }
  else if (nt < s2) { Bp = B1; K = 2048; aoff = 2048; coff = N0;     nloc = (nt - s1) * 256; }
  else              { Bp = B2; K = 4096; aoff = 4096; coff = 2 * N0; nloc = (nt - s2) * 256; }
  int ldb = K;

  int srow = tid >> 3;                               // 0..63 within a sweep
  int scol = ((tid & 7) ^ ((tid >> 3) & 7)) << 3;    // pre-swizzled source chunk
  const unsigned short* Agb = A + (size_t)(m0 + srow) * 8192 + aoff + scol;
  const unsigned short* Bgb = Bp + (size_t)(nloc + (srow & 31)) * ldb + scol;
  int bs64 = (srow >> 5) << 6;                       // 0 or 64 (wave-uniform)

#define STA(buf, mh, kk)                                                                              \
  __builtin_amdgcn_global_load_lds(                                                                   \
      (const __attribute__((address_space(1))) void*)(Agb + (size_t)((mh) * 64) * 8192 + (kk)),       \
      (__attribute__((address_space(3))) void*)((char*)As[buf] + (mh) * 16384 + wave * 1024),         \
      16, 0, 0);                                                                                      \
  __builtin_amdgcn_global_load_lds(                                                                   \
      (const __attribute__((address_space(1))) void*)(Agb + (size_t)((mh) * 64 + 128) * 8192 + (kk)), \
      (__attribute__((address_space(3))) void*)((char*)As[buf] + (mh) * 16384 + 8192 + wave * 1024),  \
      16, 0, 0)

#define STB(buf, nh, kk)                                                                              \
  __builtin_amdgcn_global_load_lds(                                                                   \
      (const __attribute__((address_space(1))) void*)(Bgb + (size_t)(bs64 + (nh) * 32) * ldb + (kk)), \
      (__attribute__((address_space(3))) void*)((char*)Bs[buf] + (nh) * 16384 + wave * 1024),         \
      16, 0, 0);                                                                                      \
  __builtin_amdgcn_global_load_lds(                                                                   \
      (const __attribute__((address_space(1))) void*)(Bgb + (size_t)(bs64 + 128 + (nh) * 32) * ldb + (kk)), \
      (__attribute__((address_space(3))) void*)((char*)Bs[buf] + (nh) * 16384 + 8192 + wave * 1024),  \
      16, 0, 0)

#define RAF(buf, mh)                                                                                  \
  _Pragma("unroll") for (int mi_ = 0; mi_ < 4; ++mi_)                                                 \
  _Pragma("unroll") for (int ks_ = 0; ks_ < 2; ++ks_)                                                 \
      af[mi_][ks_] = *(const bf16x8*)((const char*)As[buf] +                                          \
          (((mh) * 128 + wm64 + mi_ * 16 + lane15) << 7) + (((ks_ * 4 + lane4) ^ l7) << 4))

#define RBF(dst, buf, nh)                                                                             \
  _Pragma("unroll") for (int ni_ = 0; ni_ < 2; ++ni_)                                                 \
  _Pragma("unroll") for (int ks_ = 0; ks_ < 2; ++ks_)                                                 \
      dst[ni_][ks_] = *(const bf16x8*)((const char*)Bs[buf] +                                         \
          (((nh) * 128 + wn32 + ni_ * 16 + lane15) << 7) + (((ks_ * 4 + lane4) ^ l7) << 4))

#define MM(mh, nh, bF)                                                                                \
  _Pragma("unroll") for (int mi_ = 0; mi_ < 4; ++mi_)                                                 \
  _Pragma("unroll") for (int ni_ = 0; ni_ < 2; ++ni_)                                                 \
  _Pragma("unroll") for (int ks_ = 0; ks_ < 2; ++ks_)                                                 \
      acc[(mh) * 4 + mi_][(nh) * 2 + ni_] = __builtin_amdgcn_mfma_f32_16x16x32_bf16(                  \
          af[mi_][ks_], bF[ni_][ks_], acc[(mh) * 4 + mi_][(nh) * 2 + ni_], 0, 0, 0)

#define BAR() __builtin_amdgcn_s_barrier()
#define LGKM0() asm volatile("s_waitcnt lgkmcnt(0)" ::: "memory")
#define LGKM8() asm volatile("s_waitcnt lgkmcnt(8)" ::: "memory")
#define VM6() asm volatile("s_waitcnt vmcnt(6)" ::: "memory")

  bf16x8 af[4][2], b0r[2][2], b1r[2][2];
  const floatx4 fz = {0.f, 0.f, 0.f, 0.f};
  floatx4 acc[8][4];
#pragma unroll
  for (int a = 0; a < 8; ++a)
#pragma unroll
    for (int b = 0; b < 4; ++b) acc[a][b] = fz;

  // Prologue: T0 (buf0,k=0) fully; T1 (buf1,k=64) minus A-mh1 (= 7 half-tiles,
  // 14 loads). vmcnt(6) -> T0's 8 loads landed.
  STA(0, 0, 0); STB(0, 0, 0); STB(0, 1, 0); STA(0, 1, 0);
  STA(1, 0, 64); STB(1, 0, 64); STB(1, 1, 64);
  VM6();
  BAR();

  for (int k0 = 0; k0 < K; k0 += 128) {
    // ---- P1: quad(0,0) of tile A (buf0); stage Tb.A-mh1 (buf1, freed prev P7)
    RAF(0, 0); RBF(b0r, 0, 0);
    STA(1, 1, k0 + 64);
    LGKM8();
    BAR(); LGKM0();
    __builtin_amdgcn_s_setprio(1); MM(0, 0, b0r); __builtin_amdgcn_s_setprio(0);
    BAR();
    // ---- P2: quad(0,1); stage Ta'.A-mh0 (buf0, freed P1)
    RBF(b1r, 0, 1);
    STA(0, 0, k0 + 128);
    BAR(); LGKM0();
    __builtin_amdgcn_s_setprio(1); MM(0, 1, b1r); __builtin_amdgcn_s_setprio(0);
    BAR();
    // ---- P3: quad(1,0); stage Ta'.B-nh0 (freed P1)
    RAF(0, 1);
    STB(0, 0, k0 + 128);
    BAR(); LGKM0();
    __builtin_amdgcn_s_setprio(1); MM(1, 0, b0r); __builtin_amdgcn_s_setprio(0);
    BAR();
    // ---- P4: quad(1,1); stage Ta'.B-nh1 (freed P2); counted vmcnt
    STB(0, 1, k0 + 128);
    BAR(); LGKM0();
    __builtin_amdgcn_s_setprio(1); MM(1, 1, b1r); __builtin_amdgcn_s_setprio(0);
    VM6();
    BAR();
    // ---- P5: tile B (buf1) quad(0,0); stage Ta'.A-mh1 (freed P3)
    RAF(1, 0); RBF(b0r, 1, 0);
    STA(0, 1, k0 + 128);
    LGKM8();
    BAR(); LGKM0();
    __builtin_amdgcn_s_setprio(1); MM(0, 0, b0r); __builtin_amdgcn_s_setprio(0);
    BAR();
    // ---- P6: quad(0,1); stage Tb'.A-mh0 (buf1, freed P5)
    RBF(b1r, 1, 1);
    STA(1, 0, k0 + 192);
    BAR(); LGKM0();
    __builtin_amdgcn_s_setprio(1); MM(0, 1, b1r); __builtin_amdgcn_s_setprio(0);
    BAR();
    // ---- P7: quad(1,0); stage Tb'.B-nh0 (freed P5)
    RAF(1, 1);
    STB(1, 0, k0 + 192);
    BAR(); LGKM0();
    __builtin_amdgcn_s_setprio(1); MM(1, 0, b0r); __builtin_amdgcn_s_setprio(0);
    BAR();
    // ---- P8: quad(1,1); stage Tb'.B-nh1 (freed P6); counted vmcnt
    STB(1, 1, k0 + 192);
    BAR(); LGKM0();
    __builtin_amdgcn_s_setprio(1); MM(1, 1, b1r); __builtin_amdgcn_s_setprio(0);
    VM6();
    BAR();
  }
  asm volatile("s_waitcnt vmcnt(0)" ::: "memory");

  // epilogue: C/D layout col=lane&15, row=(lane>>4)*4+r
#pragma unroll
  for (int ni = 0; ni < 4; ++ni) {
    int col = coff + nloc + wn * 64 + (ni >> 1) * 32 + (ni & 1) * 16 + lane15;
#pragma unroll
    for (int mi = 0; mi < 8; ++mi) {
      int row = m0 + wm * 128 + (mi >> 2) * 64 + (mi & 3) * 16 + lane4 * 4;
      if (Cb) {
#pragma unroll
        for (int r = 0; r < 4; ++r)
          Cb[(size_t)(row + r) * ldc + col] = f2bf(acc[mi][ni][r]);
      } else {
#pragma unroll
        for (int r = 0; r < 4; ++r)
          Cf[(size_t)(row + r) * ldc + col] = acc[mi][ni][r];
      }
    }
  }
#undef STA
#undef STB
#undef RAF
#undef RBF
#undef MM
#undef BAR
#undef LGKM0
#undef LGKM8
#undef VM6
}

// ---------- inverse-DFT (+b2, /4) -> 4x LayerNorm -> relu -> forward-DFT -> h1s bf16 ----------
__global__ __launch_bounds__(256) void ln_spec_kernel(const unsigned short* __restrict__ C2,
                                                      const float* __restrict__ b2,
                                                      const float* __restrict__ ln_g,
                                                      const float* __restrict__ ln_b,
                                                      unsigned short* __restrict__ h1s) {
  int t = threadIdx.x;
  size_t base = (size_t)blockIdx.x * 8192;
  const ushort4* p = (const ushort4*)(C2 + base);   // planes: v0|v2|vr|vi (512 ushort4 each)
  const float4* bp2 = (const float4*)b2;
  float4 y[4][2];
  float s[4] = {0, 0, 0, 0}, q[4] = {0, 0, 0, 0};
#pragma unroll
  for (int hl = 0; hl < 2; ++hl) {
    int j = hl * 256 + t;
    ushort4 u0 = p[j], u2 = p[512 + j], ur = p[1024 + j], ui = p[1536 + j];
    float4 bb = bp2[j];
#define DO(c)                                                   \
  {                                                             \
    float v0 = bf2f(u0.c), v2 = bf2f(u2.c);                     \
    float vr = bf2f(ur.c), vi = bf2f(ui.c);                     \
    float e0 = 0.25f * (v0 + v2 + 2.f * vr) + bb.c;             \
    float e1 = 0.25f * (v0 - v2 - 2.f * vi) + bb.c;             \
    float e2 = 0.25f * (v0 + v2 - 2.f * vr) + bb.c;             \
    float e3 = 0.25f * (v0 - v2 + 2.f * vi) + bb.c;             \
    y[0][hl].c = e0; y[1][hl].c = e1; y[2][hl].c = e2; y[3][hl].c = e3; \
    s[0] += e0; q[0] += e0 * e0; s[1] += e1; q[1] += e1 * e1;   \
    s[2] += e2; q[2] += e2 * e2; s[3] += e3; q[3] += e3 * e3;   \
  }
    DO(x) DO(y) DO(z) DO(w)
#undef DO
  }
#pragma unroll
  for (int off = 32; off > 0; off >>= 1)
#pragma unroll
    for (int g = 0; g < 4; ++g) {
      s[g] += __shfl_down(s[g], off, 64);
      q[g] += __shfl_down(q[g], off, 64);
    }
  __shared__ float rs[4][4], rq[4][4];
  int w = t >> 6, l = t & 63;
  if (l == 0)
#pragma unroll
    for (int g = 0; g < 4; ++g) { rs[w][g] = s[g]; rq[w][g] = q[g]; }
  __syncthreads();
  float mean[4], rstd[4];
#pragma unroll
  for (int g = 0; g < 4; ++g) {
    float ss = rs[0][g] + rs[1][g] + rs[2][g] + rs[3][g];
    float qq = rq[0][g] + rq[1][g] + rq[2][g] + rq[3][g];
    mean[g] = ss * (1.f / HID);
    float var = qq * (1.f / HID) - mean[g] * mean[g];
    rstd[g] = rsqrtf(var + 1e-5f);
  }
  const float4* gp = (const float4*)ln_g;
  const float4* lbp = (const float4*)ln_b;
#pragma unroll
  for (int hl = 0; hl < 2; ++hl) {
    int j = hl * 256 + t;
    float4 gg = gp[j], lb = lbp[j];
    ushort4 o[4];
#define DO(c)                                                               \
  {                                                                         \
    float h0 = fmaxf((y[0][hl].c - mean[0]) * rstd[0] * gg.c + lb.c, 0.f);  \
    float h1 = fmaxf((y[1][hl].c - mean[1]) * rstd[1] * gg.c + lb.c, 0.f);  \
    float h2 = fmaxf((y[2][hl].c - mean[2]) * rstd[2] * gg.c + lb.c, 0.f);  \
    float h3 = fmaxf((y[3][hl].c - mean[3]) * rstd[3] * gg.c + lb.c, 0.f);  \
    o[0].c = f2bf(h0 + h1 + h2 + h3);                                       \
    o[1].c = f2bf(h0 - h1 + h2 - h3);                                       \
    o[2].c = f2bf(h0 - h2);                                                 \
    o[3].c = f2bf(h3 - h1);                                                 \
  }
    DO(x) DO(y) DO(z) DO(w)
#undef DO
    size_t ob = (size_t)blockIdx.x * 8192;
#pragma unroll
    for (int pl = 0; pl < 4; ++pl)
      ((ushort4*)(h1s + ob + pl * 2048))[j] = o[pl];
  }
}

// ---------- final inverse-DFT (+b3, /4): Z (Mc x 2048 f32 [z0|z2|zr|zi]) -> out ----------
__global__ __launch_bounds__(256) void out_ep_kernel(const float* __restrict__ Z,
                                                     const float* __restrict__ b3,
                                                     float* __restrict__ out) {
  int e = blockIdx.x * 256 + threadIdx.x;
  int row = e >> 9, i = e & 511;
  size_t base = (size_t)row * 2048;
  float z0 = Z[base + i], z2 = Z[base + 512 + i];
  float zr = Z[base + 1024 + i], zi = Z[base + 1536 + i];
  float bv = b3[i];
  out[base + i]        = 0.25f * (z0 + z2 + 2.f * zr) + bv;
  out[base + 512 + i]  = 0.25f * (z0 - z2 - 2.f * zi) + bv;
  out[base + 1024 + i] = 0.25f * (z0 + z2 - 2.f * zr) + bv;
  out[base + 1536 + i] = 0.25f * (z0 - z2 + 2.f * zi) + bv;
}

extern "C" void kernel_launch(void* const* d_in, const int* in_sizes, int n_in,
                              void* d_out, int out_size, void* d_ws, size_t ws_size,
                              hipStream_t stream) {
  const float* ins = (const float*)d_in[0];
  const float* w1  = (const float*)d_in[1];
  const float* b1  = (const float*)d_in[2];
  const float* w2  = (const float*)d_in[3];
  const float* b2  = (const float*)d_in[4];
  const float* w3  = (const float*)d_in[5];
  const float* b3  = (const float*)d_in[6];
  const float* lng = (const float*)d_in[7];
  const float* lnb = (const float*)d_in[8];
  float* out = (float*)d_out;
  char* ws = (char*)d_ws;

  // Spectral weights (bf16), persistent at base of ws.
  unsigned short* W0s2 = (unsigned short*)ws;
  unsigned short* W2s2 = W0s2 + 4194304;
  unsigned short* Bc2  = W2s2 + 4194304;
  unsigned short* W0s3 = Bc2 + 16777216;
  unsigned short* W2s3 = W0s3 + 1048576;
  unsigned short* Bc3  = W2s3 + 1048576;
  const size_t WT_BYTES = 62914560ull;
  char* chunk_base = ws + WT_BYTES;

  // Per chunk: h1s bf16 Mc*8192 + C2 bf16 Mc*8192 (Z f32 Mc*2048 aliases C2).
  // Mc must be a multiple of 256 (256x256 GEMM tiles).
  static const int Pcand[8] = {1, 2, 4, 5, 8, 10, 20, 40};
  int P = 40;
  for (int pi = 0; pi < 8; ++pi) {
    size_t mc = (size_t)MROWS / Pcand[pi];
    size_t need = WT_BYTES + mc * 8192 * 2 * 2 + 256;
    if (need <= ws_size) { P = Pcand[pi]; break; }
  }
  const int Mc = MROWS / P;
  unsigned short* h1s = (unsigned short*)chunk_base;                     // Mc x 8192 bf16
  unsigned short* C2  = (unsigned short*)(chunk_base + (size_t)Mc * 8192 * 2);
  float*          Z   = (float*)C2;                                      // Mc x 2048 f32 (alias)

  wtrans_kernel<2048><<<4096, 256, 0, stream>>>(w2, W0s2, W2s2, Bc2);
  wtrans_kernel<512><<<1024, 256, 0, stream>>>(w3, W0s3, W2s3, Bc3);

  for (int c = 0; c < P; ++c) {
    int row0 = c * Mc;
    layer1_kernel<<<dim3(Mc / 32, 8), 256, 0, stream>>>(ins, w1, b1, h1s, row0);
    // L2 spectral: n-tiles [0,8)=V0 (K=2048), [8,16)=V2, [16,32)=Bc (K=4096); bf16 out
    gemm_spec<<<dim3(32, Mc / 256), 512, 0, stream>>>(h1s, W0s2, W2s2, Bc2, nullptr, C2,
                                                      8, 16, 16, 2048, 8192);
    ln_spec_kernel<<<Mc, 256, 0, stream>>>(C2, b2, lng, lnb, h1s);
    // L3 spectral: n-tiles [0,2)=V0', [2,4)=V2', [4,8)=Bc' -> Z f32 (ldc 2048)
    gemm_spec<<<dim3(8, Mc / 256), 512, 0, stream>>>(h1s, W0s3, W2s3, Bc3, Z, nullptr,
                                                     2, 4, 4, 512, 2048);
    out_ep_kernel<<<Mc * 2, 256, 0, stream>>>(Z, b3, out + (size_t)row0 * 2048);
  }
}

// Round 3
// 1001.419 us; speedup vs baseline: 1.2730x; 1.2282x over previous
//
#include <hip/hip_runtime.h>
#include <stdint.h>

// RotEncoderMLP via Z4-spectral (DFT) decomposition of the C4 group convs.
//   x^[0]=x0+x1+x2+x3, x^[2]=x0-x1+x2-x3, x^[1]=ur+i*ui (ur=x0-x2, ui=x3-x1)
//   y^[w] = conj(W^[w]) . x^[w];  y[g] = (1/4)[y^0 + (-1)^g y^2 + 2 Re(y^1 i^g)]
// MACs: 16*HID^2 -> 6*HID^2.
// R7: 256x256 8-phase pipelined GEMM (m201 template: T2+T3+T4+T5).
// R8: balanced panels (helped +8%; occupancy still 15% of 25% cap).
// R9: counters showed the real hole = grid-level idleness (duty 60%: 2.5 rounds
// of 1-block/CU heterogeneous tiles) + L3 underfill (160 blocks / 256 CUs).
//   (a) persistent-block GEMM: 256 blocks snake an LPT work list (long-K first;
//       pass p -> tile p*256+b / (p+1)*256-1-b) => 94% packing, no re-dispatch.
//   (b) L3 fused across chunks: L2 writes pre-LN spectral into full-rows H2,
//       LN runs in-place on H2 (row lives in regs), one L3 GEMM over 10240 rows
//       (320 tiles snake-packed). Z aliases h1s. Falls back to chunked if ws
//       is too small. Inner 8-phase schedule untouched (two-lane discipline).

#define HID 2048
#define MROWS 10240

typedef float floatx4 __attribute__((ext_vector_type(4)));
typedef __bf16 bf16x8 __attribute__((ext_vector_type(8)));

__device__ __forceinline__ unsigned short f2bf(float f) {
  union { float f; unsigned int u; } v; v.f = f;
  unsigned int r = v.u + 0x7fffu + ((v.u >> 16) & 1u);  // RNE
  return (unsigned short)(r >> 16);
}
__device__ __forceinline__ float bf2f(unsigned short s) {
  union { unsigned int u; float f; } v; v.u = ((unsigned int)s) << 16;
  return v.f;
}

// ---------- spectral weight transform: w (4,NO,2048) f32 -> W0s, W2s (NO x 2048 bf16),
// Bc (2*NO x 4096 bf16) = [[Vr, -Vi],[Vi, Vr]] ----------
template <int NO>
__global__ __launch_bounds__(256) void wtrans_kernel(const float* __restrict__ w,
                                                     unsigned short* __restrict__ W0s,
                                                     unsigned short* __restrict__ W2s,
                                                     unsigned short* __restrict__ Bc) {
  int idx = blockIdx.x * 256 + threadIdx.x;       // i * 512 + j4
  int i = idx >> 9, j4 = idx & 511;
  const float4* wp = (const float4*)w;
  float4 w0 = wp[0 * NO * 512 + i * 512 + j4];
  float4 w1 = wp[1 * NO * 512 + i * 512 + j4];
  float4 w2 = wp[2 * NO * 512 + i * 512 + j4];
  float4 w3 = wp[3 * NO * 512 + i * 512 + j4];
  ushort4 s0, s2, vr, vi, nvi;
#define DO(c)                                        \
  s0.c = f2bf(w0.c + w1.c + w2.c + w3.c);            \
  s2.c = f2bf(w0.c - w1.c + w2.c - w3.c);            \
  vr.c = f2bf(w0.c - w2.c);                          \
  vi.c = f2bf(w1.c - w3.c);                          \
  nvi.c = f2bf(-(w1.c - w3.c));
  DO(x) DO(y) DO(z) DO(w)
#undef DO
  ((ushort4*)W0s)[i * 512 + j4] = s0;
  ((ushort4*)W2s)[i * 512 + j4] = s2;
  ((ushort4*)Bc)[i * 1024 + j4] = vr;            // row i:    [Vr | -Vi]
  ((ushort4*)Bc)[i * 1024 + 512 + j4] = nvi;
  ((ushort4*)Bc)[(NO + i) * 1024 + j4] = vi;     // row NO+i: [Vi |  Vr]
  ((ushort4*)Bc)[(NO + i) * 1024 + 512 + j4] = vr;
}

// ---------- orbit-stack + layer1 + relu + forward-DFT -> h1s bf16 (Mc x 8192: [u0|u2|ur|ui]) ----------
__global__ __launch_bounds__(256) void layer1_kernel(const float* __restrict__ ins,
                                                     const float* __restrict__ w1,
                                                     const float* __restrict__ b1,
                                                     unsigned short* __restrict__ h1s,
                                                     int row0) {
  __shared__ float orbs[32][28];
  int t = threadIdx.x;
  int b0 = blockIdx.x * 32;            // chunk-local
  int i = blockIdx.y * 256 + t;
  if (t < 32) {
    const float* x = ins + (size_t)(row0 + b0 + t) * 25;
    float v[25];
#pragma unroll
    for (int p = 0; p < 25; ++p) v[p] = x[p];
    float* o = orbs[t];
    o[0] = v[12]; o[7] = v[12]; o[14] = v[12]; o[21] = v[12];
#pragma unroll
    for (int r = 0; r < 2; ++r)
#pragma unroll
      for (int c = 0; c < 3; ++c) {
        int m = 1 + r * 3 + c;
        o[m]      = v[r * 5 + c];
        o[7 + m]  = v[c * 5 + (4 - r)];
        o[14 + m] = v[(4 - r) * 5 + (4 - c)];
        o[21 + m] = v[(4 - c) * 5 + r];
      }
  }
  __syncthreads();
  float w[4][7];
#pragma unroll
  for (int r = 0; r < 4; ++r)
#pragma unroll
    for (int j = 0; j < 7; ++j) w[r][j] = w1[(r * HID + i) * 7 + j];
  float bias = b1[i];
  for (int s = 0; s < 32; ++s) {
    float a[4] = {bias, bias, bias, bias};
#pragma unroll
    for (int hh = 0; hh < 4; ++hh)
#pragma unroll
      for (int j = 0; j < 7; ++j) {
        float ov = orbs[s][hh * 7 + j];
#pragma unroll
        for (int g = 0; g < 4; ++g) a[g] += w[(hh - g) & 3][j] * ov;
      }
    float h0 = fmaxf(a[0], 0.f), h1 = fmaxf(a[1], 0.f);
    float h2 = fmaxf(a[2], 0.f), h3 = fmaxf(a[3], 0.f);
    size_t base = (size_t)(b0 + s) * 8192 + i;
    h1s[base]        = f2bf(h0 + h1 + h2 + h3);  // u0
    h1s[base + 2048] = f2bf(h0 - h1 + h2 - h3);  // u2
    h1s[base + 4096] = f2bf(h0 - h2);            // ur
    h1s[base + 6144] = f2bf(h3 - h1);            // ui
  }
}

// ---------- persistent 256x256 8-phase pipelined bf16 MFMA GEMM ----------
// Work list (LPT order): tiles [0,NTL) = long-K (Bc segment, nt = s2 + wt/MTN),
// tiles [NTL,NT) = short-K (nt = (wt-NTL)/MTN in [0,s2)); mt fastest within an
// nt-column so a 256-wide concurrent window touches few B panels. 256 blocks
// snake: pass p -> tile p*G+b (even) / (p+1)*G-1-b (odd).
// n-tile routing: nt<s1: B0,K=2048,aoff=0; nt<s2: B1,K=2048,aoff=2048; else B2,K=4096,aoff=4096.
// Output: bf16 to Cb (if non-null) else f32 to Cf.
// LDS row remap (each half-tile = 2 contiguous 64-row global_load_lds sweeps):
//   A: lrow = mh*128 + sweep*64 + r;  B: lrow = nh*128 + (r>>5)*32 + ... per STB.
// Chunk swizzle: LDS (lrow, ch) holds global k-chunk ch ^ (lrow&7); staged by
// pre-swizzling the global source column; read with ch = c ^ (lane15&7).

__global__ __launch_bounds__(512, 2) void gemm_spec(const unsigned short* __restrict__ A,
                                                    const unsigned short* __restrict__ B0,
                                                    const unsigned short* __restrict__ B1,
                                                    const unsigned short* __restrict__ B2,
                                                    float* __restrict__ Cf,
                                                    unsigned short* __restrict__ Cb,
                                                    int s1, int s2, int N0, int ldc,
                                                    int NT, int NTL, int MTN) {
  __shared__ __align__(16) unsigned short As[2][16384];
  __shared__ __align__(16) unsigned short Bs[2][16384];
  int tid = threadIdx.x;
  int wave = tid >> 6, lane = tid & 63;
  int lane15 = lane & 15, lane4 = lane >> 4, l7 = lane15 & 7;
  int wm = wave >> 2, wn = wave & 3;
  int wm64 = wm << 6, wn32 = wn << 5;

  int srow = tid >> 3;                               // 0..63 within a sweep
  int scol = ((tid & 7) ^ ((tid >> 3) & 7)) << 3;    // pre-swizzled source chunk
  int bs64 = (srow >> 5) << 6;                       // 0 or 64 (wave-uniform)

#define STA(buf, mh, kk)                                                                              \
  __builtin_amdgcn_global_load_lds(                                                                   \
      (const __attribute__((address_space(1))) void*)(Agb + (size_t)((mh) * 64) * 8192 + (kk)),       \
      (__attribute__((address_space(3))) void*)((char*)As[buf] + (mh) * 16384 + wave * 1024),         \
      16, 0, 0);                                                                                      \
  __builtin_amdgcn_global_load_lds(                                                                   \
      (const __attribute__((address_space(1))) void*)(Agb + (size_t)((mh) * 64 + 128) * 8192 + (kk)), \
      (__attribute__((address_space(3))) void*)((char*)As[buf] + (mh) * 16384 + 8192 + wave * 1024),  \
      16, 0, 0)

#define STB(buf, nh, kk)                                                                              \
  __builtin_amdgcn_global_load_lds(                                                                   \
      (const __attribute__((address_space(1))) void*)(Bgb + (size_t)(bs64 + (nh) * 32) * ldb + (kk)), \
      (__attribute__((address_space(3))) void*)((char*)Bs[buf] + (nh) * 16384 + wave * 1024),         \
      16, 0, 0);                                                                                      \
  __builtin_amdgcn_global_load_lds(                                                                   \
      (const __attribute__((address_space(1))) void*)(Bgb + (size_t)(bs64 + 128 + (nh) * 32) * ldb + (kk)), \
      (__attribute__((address_space(3))) void*)((char*)Bs[buf] + (nh) * 16384 + 8192 + wave * 1024),  \
      16, 0, 0)

#define RAF(buf, mh)                                                                                  \
  _Pragma("unroll") for (int mi_ = 0; mi_ < 4; ++mi_)                                                 \
  _Pragma("unroll") for (int ks_ = 0; ks_ < 2; ++ks_)                                                 \
      af[mi_][ks_] = *(const bf16x8*)((const char*)As[buf] +                                          \
          (((mh) * 128 + wm64 + mi_ * 16 + lane15) << 7) + (((ks_ * 4 + lane4) ^ l7) << 4))

#define RBF(dst, buf, nh)                                                                             \
  _Pragma("unroll") for (int ni_ = 0; ni_ < 2; ++ni_)                                                 \
  _Pragma("unroll") for (int ks_ = 0; ks_ < 2; ++ks_)                                                 \
      dst[ni_][ks_] = *(const bf16x8*)((const char*)Bs[buf] +                                         \
          (((nh) * 128 + wn32 + ni_ * 16 + lane15) << 7) + (((ks_ * 4 + lane4) ^ l7) << 4))

#define MM(mh, nh, bF)                                                                                \
  _Pragma("unroll") for (int mi_ = 0; mi_ < 4; ++mi_)                                                 \
  _Pragma("unroll") for (int ni_ = 0; ni_ < 2; ++ni_)                                                 \
  _Pragma("unroll") for (int ks_ = 0; ks_ < 2; ++ks_)                                                 \
      acc[(mh) * 4 + mi_][(nh) * 2 + ni_] = __builtin_amdgcn_mfma_f32_16x16x32_bf16(                  \
          af[mi_][ks_], bF[ni_][ks_], acc[(mh) * 4 + mi_][(nh) * 2 + ni_], 0, 0, 0)

#define BAR() __builtin_amdgcn_s_barrier()
#define LGKM0() asm volatile("s_waitcnt lgkmcnt(0)" ::: "memory")
#define LGKM8() asm volatile("s_waitcnt lgkmcnt(8)" ::: "memory")
#define VM6() asm volatile("s_waitcnt vmcnt(6)" ::: "memory")

  bf16x8 af[4][2], b0r[2][2], b1r[2][2];
  const floatx4 fz = {0.f, 0.f, 0.f, 0.f};
  floatx4 acc[8][4];

  int G = (int)gridDim.x;
  for (int pass = 0;; ++pass) {
    int base = pass * G;
    if (base >= NT) break;
    int wt = (pass & 1) ? (base + G - 1 - (int)blockIdx.x) : (base + (int)blockIdx.x);
    if (wt >= NT) continue;

    int mt, nt;
    if (wt < NTL) { int j = wt / MTN; nt = s2 + j; mt = wt - j * MTN; }
    else          { int w2_ = wt - NTL; int j = w2_ / MTN; nt = j; mt = w2_ - j * MTN; }
    int m0 = mt * 256;

    const unsigned short* Bp;
    int K, aoff, coff, nloc;
    if (nt < s1)      { Bp = B0; K = 2048; aoff = 0;    coff = 0;      nloc = nt * 256; }
    else if (nt < s2) { Bp = B1; K = 2048; aoff = 2048; coff = N0;     nloc = (nt - s1) * 256; }
    else              { Bp = B2; K = 4096; aoff = 4096; coff = 2 * N0; nloc = (nt - s2) * 256; }
    int ldb = K;

    const unsigned short* Agb = A + (size_t)(m0 + srow) * 8192 + aoff + scol;
    const unsigned short* Bgb = Bp + (size_t)(nloc + (srow & 31)) * ldb + scol;

#pragma unroll
    for (int a = 0; a < 8; ++a)
#pragma unroll
      for (int b = 0; b < 4; ++b) acc[a][b] = fz;

    // Prologue: T0 (buf0,k=0) fully; T1 (buf1,k=64) minus A-mh1 (7 half-tiles,
    // 14 loads). vmcnt(6) -> T0's 8 loads landed (also drains prev epilogue).
    STA(0, 0, 0); STB(0, 0, 0); STB(0, 1, 0); STA(0, 1, 0);
    STA(1, 0, 64); STB(1, 0, 64); STB(1, 1, 64);
    VM6();
    BAR();

    for (int k0 = 0; k0 < K; k0 += 128) {
      // ---- P1: quad(0,0) of tile A (buf0); stage Tb.A-mh1 (buf1, freed prev P7)
      RAF(0, 0); RBF(b0r, 0, 0);
      STA(1, 1, k0 + 64);
      LGKM8();
      BAR(); LGKM0();
      __builtin_amdgcn_s_setprio(1); MM(0, 0, b0r); __builtin_amdgcn_s_setprio(0);
      BAR();
      // ---- P2: quad(0,1); stage Ta'.A-mh0 (buf0, freed P1)
      RBF(b1r, 0, 1);
      STA(0, 0, k0 + 128);
      BAR(); LGKM0();
      __builtin_amdgcn_s_setprio(1); MM(0, 1, b1r); __builtin_amdgcn_s_setprio(0);
      BAR();
      // ---- P3: quad(1,0); stage Ta'.B-nh0 (freed P1)
      RAF(0, 1);
      STB(0, 0, k0 + 128);
      BAR(); LGKM0();
      __builtin_amdgcn_s_setprio(1); MM(1, 0, b0r); __builtin_amdgcn_s_setprio(0);
      BAR();
      // ---- P4: quad(1,1); stage Ta'.B-nh1 (freed P2); counted vmcnt
      STB(0, 1, k0 + 128);
      BAR(); LGKM0();
      __builtin_amdgcn_s_setprio(1); MM(1, 1, b1r); __builtin_amdgcn_s_setprio(0);
      VM6();
      BAR();
      // ---- P5: tile B (buf1) quad(0,0); stage Ta'.A-mh1 (freed P3)
      RAF(1, 0); RBF(b0r, 1, 0);
      STA(0, 1, k0 + 128);
      LGKM8();
      BAR(); LGKM0();
      __builtin_amdgcn_s_setprio(1); MM(0, 0, b0r); __builtin_amdgcn_s_setprio(0);
      BAR();
      // ---- P6: quad(0,1); stage Tb'.A-mh0 (buf1, freed P5)
      RBF(b1r, 1, 1);
      STA(1, 0, k0 + 192);
      BAR(); LGKM0();
      __builtin_amdgcn_s_setprio(1); MM(0, 1, b1r); __builtin_amdgcn_s_setprio(0);
      BAR();
      // ---- P7: quad(1,0); stage Tb'.B-nh0 (freed P5)
      RAF(1, 1);
      STB(1, 0, k0 + 192);
      BAR(); LGKM0();
      __builtin_amdgcn_s_setprio(1); MM(1, 0, b0r); __builtin_amdgcn_s_setprio(0);
      BAR();
      // ---- P8: quad(1,1); stage Tb'.B-nh1 (freed P6); counted vmcnt
      STB(1, 1, k0 + 192);
      BAR(); LGKM0();
      __builtin_amdgcn_s_setprio(1); MM(1, 1, b1r); __builtin_amdgcn_s_setprio(0);
      VM6();
      BAR();
    }
    asm volatile("s_waitcnt vmcnt(0)" ::: "memory");

    // epilogue: C/D layout col=lane&15, row=(lane>>4)*4+r
#pragma unroll
    for (int ni = 0; ni < 4; ++ni) {
      int col = coff + nloc + wn * 64 + (ni >> 1) * 32 + (ni & 1) * 16 + lane15;
#pragma unroll
      for (int mi = 0; mi < 8; ++mi) {
        int row = m0 + wm * 128 + (mi >> 2) * 64 + (mi & 3) * 16 + lane4 * 4;
        if (Cb) {
#pragma unroll
          for (int r = 0; r < 4; ++r)
            Cb[(size_t)(row + r) * ldc + col] = f2bf(acc[mi][ni][r]);
        } else {
#pragma unroll
          for (int r = 0; r < 4; ++r)
            Cf[(size_t)(row + r) * ldc + col] = acc[mi][ni][r];
        }
      }
    }
  }
#undef STA
#undef STB
#undef RAF
#undef RBF
#undef MM
#undef BAR
#undef LGKM0
#undef LGKM8
#undef VM6
}

// ---------- inverse-DFT (+b2, /4) -> 4x LayerNorm -> relu -> forward-DFT -> out bf16 ----------
// NOTE: may be called with h1s == C2 (in-place): each row is fully register-
// resident between read and write (reads all precede the reduction barrier).
__global__ __launch_bounds__(256) void ln_spec_kernel(const unsigned short* C2,
                                                      const float* __restrict__ b2,
                                                      const float* __restrict__ ln_g,
                                                      const float* __restrict__ ln_b,
                                                      unsigned short* h1s) {
  int t = threadIdx.x;
  size_t base = (size_t)blockIdx.x * 8192;
  const ushort4* p = (const ushort4*)(C2 + base);   // planes: v0|v2|vr|vi (512 ushort4 each)
  const float4* bp2 = (const float4*)b2;
  float4 y[4][2];
  float s[4] = {0, 0, 0, 0}, q[4] = {0, 0, 0, 0};
#pragma unroll
  for (int hl = 0; hl < 2; ++hl) {
    int j = hl * 256 + t;
    ushort4 u0 = p[j], u2 = p[512 + j], ur = p[1024 + j], ui = p[1536 + j];
    float4 bb = bp2[j];
#define DO(c)                                                   \
  {                                                             \
    float v0 = bf2f(u0.c), v2 = bf2f(u2.c);                     \
    float vr = bf2f(ur.c), vi = bf2f(ui.c);                     \
    float e0 = 0.25f * (v0 + v2 + 2.f * vr) + bb.c;             \
    float e1 = 0.25f * (v0 - v2 - 2.f * vi) + bb.c;             \
    float e2 = 0.25f * (v0 + v2 - 2.f * vr) + bb.c;             \
    float e3 = 0.25f * (v0 - v2 + 2.f * vi) + bb.c;             \
    y[0][hl].c = e0; y[1][hl].c = e1; y[2][hl].c = e2; y[3][hl].c = e3; \
    s[0] += e0; q[0] += e0 * e0; s[1] += e1; q[1] += e1 * e1;   \
    s[2] += e2; q[2] += e2 * e2; s[3] += e3; q[3] += e3 * e3;   \
  }
    DO(x) DO(y) DO(z) DO(w)
#undef DO
  }
#pragma unroll
  for (int off = 32; off > 0; off >>= 1)
#pragma unroll
    for (int g = 0; g < 4; ++g) {
      s[g] += __shfl_down(s[g], off, 64);
      q[g] += __shfl_down(q[g], off, 64);
    }
  __shared__ float rs[4][4], rq[4][4];
  int w = t >> 6, l = t & 63;
  if (l == 0)
#pragma unroll
    for (int g = 0; g < 4; ++g) { rs[w][g] = s[g]; rq[w][g] = q[g]; }
  __syncthreads();
  float mean[4], rstd[4];
#pragma unroll
  for (int g = 0; g < 4; ++g) {
    float ss = rs[0][g] + rs[1][g] + rs[2][g] + rs[3][g];
    float qq = rq[0][g] + rq[1][g] + rq[2][g] + rq[3][g];
    mean[g] = ss * (1.f / HID);
    float var = qq * (1.f / HID) - mean[g] * mean[g];
    rstd[g] = rsqrtf(var + 1e-5f);
  }
  const float4* gp = (const float4*)ln_g;
  const float4* lbp = (const float4*)ln_b;
#pragma unroll
  for (int hl = 0; hl < 2; ++hl) {
    int j = hl * 256 + t;
    float4 gg = gp[j], lb = lbp[j];
    ushort4 o[4];
#define DO(c)                                                               \
  {                                                                         \
    float h0 = fmaxf((y[0][hl].c - mean[0]) * rstd[0] * gg.c + lb.c, 0.f);  \
    float h1 = fmaxf((y[1][hl].c - mean[1]) * rstd[1] * gg.c + lb.c, 0.f);  \
    float h2 = fmaxf((y[2][hl].c - mean[2]) * rstd[2] * gg.c + lb.c, 0.f);  \
    float h3 = fmaxf((y[3][hl].c - mean[3]) * rstd[3] * gg.c + lb.c, 0.f);  \
    o[0].c = f2bf(h0 + h1 + h2 + h3);                                       \
    o[1].c = f2bf(h0 - h1 + h2 - h3);                                       \
    o[2].c = f2bf(h0 - h2);                                                 \
    o[3].c = f2bf(h3 - h1);                                                 \
  }
    DO(x) DO(y) DO(z) DO(w)
#undef DO
    size_t ob = (size_t)blockIdx.x * 8192;
#pragma unroll
    for (int pl = 0; pl < 4; ++pl)
      ((ushort4*)(h1s + ob + pl * 2048))[j] = o[pl];
  }
}

// ---------- final inverse-DFT (+b3, /4): Z (rows x 2048 f32 [z0|z2|zr|zi]) -> out ----------
__global__ __launch_bounds__(256) void out_ep_kernel(const float* __restrict__ Z,
                                                     const float* __restrict__ b3,
                                                     float* __restrict__ out) {
  int e = blockIdx.x * 256 + threadIdx.x;
  int row = e >> 9, i = e & 511;
  size_t base = (size_t)row * 2048;
  float z0 = Z[base + i], z2 = Z[base + 512 + i];
  float zr = Z[base + 1024 + i], zi = Z[base + 1536 + i];
  float bv = b3[i];
  out[base + i]        = 0.25f * (z0 + z2 + 2.f * zr) + bv;
  out[base + 512 + i]  = 0.25f * (z0 - z2 - 2.f * zi) + bv;
  out[base + 1024 + i] = 0.25f * (z0 + z2 - 2.f * zr) + bv;
  out[base + 1536 + i] = 0.25f * (z0 - z2 + 2.f * zi) + bv;
}

extern "C" void kernel_launch(void* const* d_in, const int* in_sizes, int n_in,
                              void* d_out, int out_size, void* d_ws, size_t ws_size,
                              hipStream_t stream) {
  const float* ins = (const float*)d_in[0];
  const float* w1  = (const float*)d_in[1];
  const float* b1  = (const float*)d_in[2];
  const float* w2  = (const float*)d_in[3];
  const float* b2  = (const float*)d_in[4];
  const float* w3  = (const float*)d_in[5];
  const float* b3  = (const float*)d_in[6];
  const float* lng = (const float*)d_in[7];
  const float* lnb = (const float*)d_in[8];
  float* out = (float*)d_out;
  char* ws = (char*)d_ws;

  // Spectral weights (bf16), persistent at base of ws.
  unsigned short* W0s2 = (unsigned short*)ws;
  unsigned short* W2s2 = W0s2 + 4194304;
  unsigned short* Bc2  = W2s2 + 4194304;
  unsigned short* W0s3 = Bc2 + 16777216;
  unsigned short* W2s3 = W0s3 + 1048576;
  unsigned short* Bc3  = W2s3 + 1048576;
  const size_t WT_BYTES = 62914560ull;
  char* chunk_base = ws + WT_BYTES;

  wtrans_kernel<2048><<<4096, 256, 0, stream>>>(w2, W0s2, W2s2, Bc2);
  wtrans_kernel<512><<<1024, 256, 0, stream>>>(w3, W0s3, W2s3, Bc3);

  const size_t H1_BYTES = (size_t)5120 * 8192 * 2;      // 84 MB (== Z full f32)
  const size_t H2_BYTES = (size_t)MROWS * 8192 * 2;     // 168 MB
  const size_t need_full = WT_BYTES + H1_BYTES + H2_BYTES + 4096;

  if (ws_size >= need_full) {
    // ---- fused-L3 path: 2 chunks for L2; one full-rows L3 ----
    unsigned short* h1s = (unsigned short*)chunk_base;               // 5120 x 8192 bf16
    float*          Z   = (float*)chunk_base;                        // 10240 x 2048 f32 (alias, used after h1s dead)
    unsigned short* H2  = (unsigned short*)(chunk_base + H1_BYTES);  // 10240 x 8192 bf16
    const int Mc = 5120, MTN = Mc / 256;
    for (int c = 0; c < 2; ++c) {
      int row0 = c * Mc;
      unsigned short* H2c = H2 + (size_t)row0 * 8192;
      layer1_kernel<<<dim3(Mc / 32, 8), 256, 0, stream>>>(ins, w1, b1, h1s, row0);
      // L2 spectral -> pre-LN spectral into H2 rows of this chunk
      gemm_spec<<<256, 512, 0, stream>>>(h1s, W0s2, W2s2, Bc2, nullptr, H2c,
                                         8, 16, 2048, 8192, 32 * MTN, 16 * MTN, MTN);
      // LN in-place on H2 chunk rows
      ln_spec_kernel<<<Mc, 256, 0, stream>>>(H2c, b2, lng, lnb, H2c);
    }
    // L3 spectral over all rows: 320 tiles (160 long) snake-packed
    {
      const int MT3 = MROWS / 256;
      gemm_spec<<<256, 512, 0, stream>>>(H2, W0s3, W2s3, Bc3, Z, nullptr,
                                         2, 4, 512, 2048, 8 * MT3, 4 * MT3, MT3);
      out_ep_kernel<<<MROWS * 2, 256, 0, stream>>>(Z, b3, out);
    }
  } else {
    // ---- fallback: chunked flow (persistent-snake GEMMs) ----
    static const int Pcand[8] = {1, 2, 4, 5, 8, 10, 20, 40};
    int P = 40;
    for (int pi = 0; pi < 8; ++pi) {
      size_t mc = (size_t)MROWS / Pcand[pi];
      size_t need = WT_BYTES + mc * 8192 * 2 * 2 + 4096;
      if (need <= ws_size) { P = Pcand[pi]; break; }
    }
    const int Mc = MROWS / P, MTN = Mc / 256;
    unsigned short* h1s = (unsigned short*)chunk_base;                     // Mc x 8192 bf16
    unsigned short* C2  = (unsigned short*)(chunk_base + (size_t)Mc * 8192 * 2);
    float*          Z   = (float*)C2;                                      // Mc x 2048 f32 (alias)
    for (int c = 0; c < P; ++c) {
      int row0 = c * Mc;
      layer1_kernel<<<dim3(Mc / 32, 8), 256, 0, stream>>>(ins, w1, b1, h1s, row0);
      gemm_spec<<<256, 512, 0, stream>>>(h1s, W0s2, W2s2, Bc2, nullptr, C2,
                                         8, 16, 2048, 8192, 32 * MTN, 16 * MTN, MTN);
      ln_spec_kernel<<<Mc, 256, 0, stream>>>(C2, b2, lng, lnb, h1s);
      gemm_spec<<<256, 512, 0, stream>>>(h1s, W0s3, W2s3, Bc3, Z, nullptr,
                                         2, 4, 512, 2048, 8 * MTN, 4 * MTN, MTN);
      out_ep_kernel<<<Mc * 2, 256, 0, stream>>>(Z, b3, out + (size_t)row0 * 2048);
    }
  }
}

// Round 4
// 990.044 us; speedup vs baseline: 1.2877x; 1.0115x over previous
//
#include <hip/hip_runtime.h>
#include <stdint.h>

// RotEncoderMLP via Z4-spectral (DFT) decomposition of the C4 group convs.
//   x^[0]=x0+x1+x2+x3, x^[2]=x0-x1+x2-x3, x^[1]=ur+i*ui (ur=x0-x2, ui=x3-x1)
//   y^[w] = conj(W^[w]) . x^[w];  y[g] = (1/4)[y^0 + (-1)^g y^2 + 2 Re(y^1 i^g)]
// MACs: 16*HID^2 -> 6*HID^2.
// R7: 256x256 8-phase pipelined GEMM (m201 template: T2+T3+T4+T5).
// R8: balanced panels. R9: persistent-snake LPT work list + fused L3
// (duty 60->85%, MfmaUtil 29->37.9). Resident-eff stuck at ~45%.
// R10: (a) merge the two L2 chunks into ONE 1280-tile persistent dispatch
//      (duty quantization 3.75u->7.5u per block; removes one drain/fill)
//      when ws >= ~399 MB; guarded fallback = R9 flow.
//      (b) prefetch-slack fix: buf1 A-mh1 stage moved P1 -> prev-iter P8
//      (region free after P7); prologue = 16 loads + vmcnt(8). FIFO coverage
//      re-derived: P4 VM6 retires prevP7+prevP8; P8 VM6 retires P5+P6.

#define HID 2048
#define MROWS 10240

typedef float floatx4 __attribute__((ext_vector_type(4)));
typedef __bf16 bf16x8 __attribute__((ext_vector_type(8)));

__device__ __forceinline__ unsigned short f2bf(float f) {
  union { float f; unsigned int u; } v; v.f = f;
  unsigned int r = v.u + 0x7fffu + ((v.u >> 16) & 1u);  // RNE
  return (unsigned short)(r >> 16);
}
__device__ __forceinline__ float bf2f(unsigned short s) {
  union { unsigned int u; float f; } v; v.u = ((unsigned int)s) << 16;
  return v.f;
}

// ---------- spectral weight transform: w (4,NO,2048) f32 -> W0s, W2s (NO x 2048 bf16),
// Bc (2*NO x 4096 bf16) = [[Vr, -Vi],[Vi, Vr]] ----------
template <int NO>
__global__ __launch_bounds__(256) void wtrans_kernel(const float* __restrict__ w,
                                                     unsigned short* __restrict__ W0s,
                                                     unsigned short* __restrict__ W2s,
                                                     unsigned short* __restrict__ Bc) {
  int idx = blockIdx.x * 256 + threadIdx.x;       // i * 512 + j4
  int i = idx >> 9, j4 = idx & 511;
  const float4* wp = (const float4*)w;
  float4 w0 = wp[0 * NO * 512 + i * 512 + j4];
  float4 w1 = wp[1 * NO * 512 + i * 512 + j4];
  float4 w2 = wp[2 * NO * 512 + i * 512 + j4];
  float4 w3 = wp[3 * NO * 512 + i * 512 + j4];
  ushort4 s0, s2, vr, vi, nvi;
#define DO(c)                                        \
  s0.c = f2bf(w0.c + w1.c + w2.c + w3.c);            \
  s2.c = f2bf(w0.c - w1.c + w2.c - w3.c);            \
  vr.c = f2bf(w0.c - w2.c);                          \
  vi.c = f2bf(w1.c - w3.c);                          \
  nvi.c = f2bf(-(w1.c - w3.c));
  DO(x) DO(y) DO(z) DO(w)
#undef DO
  ((ushort4*)W0s)[i * 512 + j4] = s0;
  ((ushort4*)W2s)[i * 512 + j4] = s2;
  ((ushort4*)Bc)[i * 1024 + j4] = vr;            // row i:    [Vr | -Vi]
  ((ushort4*)Bc)[i * 1024 + 512 + j4] = nvi;
  ((ushort4*)Bc)[(NO + i) * 1024 + j4] = vi;     // row NO+i: [Vi |  Vr]
  ((ushort4*)Bc)[(NO + i) * 1024 + 512 + j4] = vr;
}

// ---------- orbit-stack + layer1 + relu + forward-DFT -> h1s bf16 (rows x 8192: [u0|u2|ur|ui]) ----------
__global__ __launch_bounds__(256) void layer1_kernel(const float* __restrict__ ins,
                                                     const float* __restrict__ w1,
                                                     const float* __restrict__ b1,
                                                     unsigned short* __restrict__ h1s,
                                                     int row0) {
  __shared__ float orbs[32][28];
  int t = threadIdx.x;
  int b0 = blockIdx.x * 32;            // chunk-local
  int i = blockIdx.y * 256 + t;
  if (t < 32) {
    const float* x = ins + (size_t)(row0 + b0 + t) * 25;
    float v[25];
#pragma unroll
    for (int p = 0; p < 25; ++p) v[p] = x[p];
    float* o = orbs[t];
    o[0] = v[12]; o[7] = v[12]; o[14] = v[12]; o[21] = v[12];
#pragma unroll
    for (int r = 0; r < 2; ++r)
#pragma unroll
      for (int c = 0; c < 3; ++c) {
        int m = 1 + r * 3 + c;
        o[m]      = v[r * 5 + c];
        o[7 + m]  = v[c * 5 + (4 - r)];
        o[14 + m] = v[(4 - r) * 5 + (4 - c)];
        o[21 + m] = v[(4 - c) * 5 + r];
      }
  }
  __syncthreads();
  float w[4][7];
#pragma unroll
  for (int r = 0; r < 4; ++r)
#pragma unroll
    for (int j = 0; j < 7; ++j) w[r][j] = w1[(r * HID + i) * 7 + j];
  float bias = b1[i];
  for (int s = 0; s < 32; ++s) {
    float a[4] = {bias, bias, bias, bias};
#pragma unroll
    for (int hh = 0; hh < 4; ++hh)
#pragma unroll
      for (int j = 0; j < 7; ++j) {
        float ov = orbs[s][hh * 7 + j];
#pragma unroll
        for (int g = 0; g < 4; ++g) a[g] += w[(hh - g) & 3][j] * ov;
      }
    float h0 = fmaxf(a[0], 0.f), h1 = fmaxf(a[1], 0.f);
    float h2 = fmaxf(a[2], 0.f), h3 = fmaxf(a[3], 0.f);
    size_t base = (size_t)(b0 + s) * 8192 + i;
    h1s[base]        = f2bf(h0 + h1 + h2 + h3);  // u0
    h1s[base + 2048] = f2bf(h0 - h1 + h2 - h3);  // u2
    h1s[base + 4096] = f2bf(h0 - h2);            // ur
    h1s[base + 6144] = f2bf(h3 - h1);            // ui
  }
}

// ---------- persistent 256x256 8-phase pipelined bf16 MFMA GEMM ----------
// Work list (LPT order): tiles [0,NTL) = long-K (Bc segment, nt = s2 + wt/MTN),
// tiles [NTL,NT) = short-K (nt = (wt-NTL)/MTN in [0,s2)); mt fastest within an
// nt-column. G blocks snake: pass p -> tile p*G+b (even) / (p+1)*G-1-b (odd).
// n-tile routing: nt<s1: B0,K=2048,aoff=0; nt<s2: B1,K=2048,aoff=2048; else B2,K=4096,aoff=4096.
// Output: bf16 to Cb (if non-null) else f32 to Cf.
// LDS row remap (each half-tile = 2 contiguous 64-row global_load_lds sweeps).
// Chunk swizzle: LDS (lrow, ch) holds global k-chunk ch ^ (lrow&7); staged by
// pre-swizzling the global source column; read with ch = c ^ (lane15&7).
// Stage ring (R10): P2:A0mh0 P3:B0nh0 P4:B0nh1 P5:A0mh1 P6:A1mh0 P7:B1nh0
// P8:B1nh1+A1mh1 (A-mh1 region free after P7's RAF). 16 loads/iter.

__global__ __launch_bounds__(512, 2) void gemm_spec(const unsigned short* __restrict__ A,
                                                    const unsigned short* __restrict__ B0,
                                                    const unsigned short* __restrict__ B1,
                                                    const unsigned short* __restrict__ B2,
                                                    float* __restrict__ Cf,
                                                    unsigned short* __restrict__ Cb,
                                                    int s1, int s2, int N0, int ldc,
                                                    int NT, int NTL, int MTN) {
  __shared__ __align__(16) unsigned short As[2][16384];
  __shared__ __align__(16) unsigned short Bs[2][16384];
  int tid = threadIdx.x;
  int wave = tid >> 6, lane = tid & 63;
  int lane15 = lane & 15, lane4 = lane >> 4, l7 = lane15 & 7;
  int wm = wave >> 2, wn = wave & 3;
  int wm64 = wm << 6, wn32 = wn << 5;

  int srow = tid >> 3;                               // 0..63 within a sweep
  int scol = ((tid & 7) ^ ((tid >> 3) & 7)) << 3;    // pre-swizzled source chunk
  int bs64 = (srow >> 5) << 6;                       // 0 or 64 (wave-uniform)

#define STA(buf, mh, kk)                                                                              \
  __builtin_amdgcn_global_load_lds(                                                                   \
      (const __attribute__((address_space(1))) void*)(Agb + (size_t)((mh) * 64) * 8192 + (kk)),       \
      (__attribute__((address_space(3))) void*)((char*)As[buf] + (mh) * 16384 + wave * 1024),         \
      16, 0, 0);                                                                                      \
  __builtin_amdgcn_global_load_lds(                                                                   \
      (const __attribute__((address_space(1))) void*)(Agb + (size_t)((mh) * 64 + 128) * 8192 + (kk)), \
      (__attribute__((address_space(3))) void*)((char*)As[buf] + (mh) * 16384 + 8192 + wave * 1024),  \
      16, 0, 0)

#define STB(buf, nh, kk)                                                                              \
  __builtin_amdgcn_global_load_lds(                                                                   \
      (const __attribute__((address_space(1))) void*)(Bgb + (size_t)(bs64 + (nh) * 32) * ldb + (kk)), \
      (__attribute__((address_space(3))) void*)((char*)Bs[buf] + (nh) * 16384 + wave * 1024),         \
      16, 0, 0);                                                                                      \
  __builtin_amdgcn_global_load_lds(                                                                   \
      (const __attribute__((address_space(1))) void*)(Bgb + (size_t)(bs64 + 128 + (nh) * 32) * ldb + (kk)), \
      (__attribute__((address_space(3))) void*)((char*)Bs[buf] + (nh) * 16384 + 8192 + wave * 1024),  \
      16, 0, 0)

#define RAF(buf, mh)                                                                                  \
  _Pragma("unroll") for (int mi_ = 0; mi_ < 4; ++mi_)                                                 \
  _Pragma("unroll") for (int ks_ = 0; ks_ < 2; ++ks_)                                                 \
      af[mi_][ks_] = *(const bf16x8*)((const char*)As[buf] +                                          \
          (((mh) * 128 + wm64 + mi_ * 16 + lane15) << 7) + (((ks_ * 4 + lane4) ^ l7) << 4))

#define RBF(dst, buf, nh)                                                                             \
  _Pragma("unroll") for (int ni_ = 0; ni_ < 2; ++ni_)                                                 \
  _Pragma("unroll") for (int ks_ = 0; ks_ < 2; ++ks_)                                                 \
      dst[ni_][ks_] = *(const bf16x8*)((const char*)Bs[buf] +                                         \
          (((nh) * 128 + wn32 + ni_ * 16 + lane15) << 7) + (((ks_ * 4 + lane4) ^ l7) << 4))

#define MM(mh, nh, bF)                                                                                \
  _Pragma("unroll") for (int mi_ = 0; mi_ < 4; ++mi_)                                                 \
  _Pragma("unroll") for (int ni_ = 0; ni_ < 2; ++ni_)                                                 \
  _Pragma("unroll") for (int ks_ = 0; ks_ < 2; ++ks_)                                                 \
      acc[(mh) * 4 + mi_][(nh) * 2 + ni_] = __builtin_amdgcn_mfma_f32_16x16x32_bf16(                  \
          af[mi_][ks_], bF[ni_][ks_], acc[(mh) * 4 + mi_][(nh) * 2 + ni_], 0, 0, 0)

#define BAR() __builtin_amdgcn_s_barrier()
#define LGKM0() asm volatile("s_waitcnt lgkmcnt(0)" ::: "memory")
#define LGKM8() asm volatile("s_waitcnt lgkmcnt(8)" ::: "memory")
#define VM6() asm volatile("s_waitcnt vmcnt(6)" ::: "memory")
#define VM8() asm volatile("s_waitcnt vmcnt(8)" ::: "memory")

  bf16x8 af[4][2], b0r[2][2], b1r[2][2];
  const floatx4 fz = {0.f, 0.f, 0.f, 0.f};
  floatx4 acc[8][4];

  int G = (int)gridDim.x;
  for (int pass = 0;; ++pass) {
    int base = pass * G;
    if (base >= NT) break;
    int wt = (pass & 1) ? (base + G - 1 - (int)blockIdx.x) : (base + (int)blockIdx.x);
    if (wt >= NT) continue;

    int mt, nt;
    if (wt < NTL) { int j = wt / MTN; nt = s2 + j; mt = wt - j * MTN; }
    else          { int w2_ = wt - NTL; int j = w2_ / MTN; nt = j; mt = w2_ - j * MTN; }
    int m0 = mt * 256;

    const unsigned short* Bp;
    int K, aoff, coff, nloc;
    if (nt < s1)      { Bp = B0; K = 2048; aoff = 0;    coff = 0;      nloc = nt * 256; }
    else if (nt < s2) { Bp = B1; K = 2048; aoff = 2048; coff = N0;     nloc = (nt - s1) * 256; }
    else              { Bp = B2; K = 4096; aoff = 4096; coff = 2 * N0; nloc = (nt - s2) * 256; }
    int ldb = K;

    const unsigned short* Agb = A + (size_t)(m0 + srow) * 8192 + aoff + scol;
    const unsigned short* Bgb = Bp + (size_t)(nloc + (srow & 31)) * ldb + scol;

#pragma unroll
    for (int a = 0; a < 8; ++a)
#pragma unroll
      for (int b = 0; b < 4; ++b) acc[a][b] = fz;

    // Prologue: T0 (buf0,k=0) then T1 (buf1,k=64), all 16 loads; vmcnt(8)
    // retires exactly T0's 8 (also drains prev epilogue stores first, FIFO).
    STA(0, 0, 0); STB(0, 0, 0); STB(0, 1, 0); STA(0, 1, 0);
    STA(1, 0, 64); STB(1, 0, 64); STB(1, 1, 64); STA(1, 1, 64);
    VM8();
    BAR();

    for (int k0 = 0; k0 < K; k0 += 128) {
      // ---- P1: quad(0,0) of tile A (buf0); no stage (moved to P8)
      RAF(0, 0); RBF(b0r, 0, 0);
      LGKM8();
      BAR(); LGKM0();
      __builtin_amdgcn_s_setprio(1); MM(0, 0, b0r); __builtin_amdgcn_s_setprio(0);
      BAR();
      // ---- P2: quad(0,1); stage Ta'.A-mh0 (buf0, freed P1)
      RBF(b1r, 0, 1);
      STA(0, 0, k0 + 128);
      BAR(); LGKM0();
      __builtin_amdgcn_s_setprio(1); MM(0, 1, b1r); __builtin_amdgcn_s_setprio(0);
      BAR();
      // ---- P3: quad(1,0); stage Ta'.B-nh0 (freed P1)
      RAF(0, 1);
      STB(0, 0, k0 + 128);
      BAR(); LGKM0();
      __builtin_amdgcn_s_setprio(1); MM(1, 0, b0r); __builtin_amdgcn_s_setprio(0);
      BAR();
      // ---- P4: quad(1,1); stage Ta'.B-nh1 (freed P2); counted vmcnt
      // outstanding here: prevP7(2)+prevP8(4)+P2..P4(6)=12 -> retire prevP7+prevP8
      STB(0, 1, k0 + 128);
      BAR(); LGKM0();
      __builtin_amdgcn_s_setprio(1); MM(1, 1, b1r); __builtin_amdgcn_s_setprio(0);
      VM6();
      BAR();
      // ---- P5: tile B (buf1) quad(0,0); stage Ta'.A-mh1 (freed P3)
      RAF(1, 0); RBF(b0r, 1, 0);
      STA(0, 1, k0 + 128);
      LGKM8();
      BAR(); LGKM0();
      __builtin_amdgcn_s_setprio(1); MM(0, 0, b0r); __builtin_amdgcn_s_setprio(0);
      BAR();
      // ---- P6: quad(0,1); stage Tb'.A-mh0 (buf1, freed P5)
      RBF(b1r, 1, 1);
      STA(1, 0, k0 + 192);
      BAR(); LGKM0();
      __builtin_amdgcn_s_setprio(1); MM(0, 1, b1r); __builtin_amdgcn_s_setprio(0);
      BAR();
      // ---- P7: quad(1,0); stage Tb'.B-nh0 (freed P5)
      RAF(1, 1);
      STB(1, 0, k0 + 192);
      BAR(); LGKM0();
      __builtin_amdgcn_s_setprio(1); MM(1, 0, b0r); __builtin_amdgcn_s_setprio(0);
      BAR();
      // ---- P8: quad(1,1); stage Tb'.B-nh1 (freed P6) + Tb'.A-mh1 (freed P7);
      // counted vmcnt: outstanding P5..P8(10) -> retire P5+P6
      STB(1, 1, k0 + 192);
      STA(1, 1, k0 + 192);
      BAR(); LGKM0();
      __builtin_amdgcn_s_setprio(1); MM(1, 1, b1r); __builtin_amdgcn_s_setprio(0);
      VM6();
      BAR();
    }
    asm volatile("s_waitcnt vmcnt(0)" ::: "memory");

    // epilogue: C/D layout col=lane&15, row=(lane>>4)*4+r
#pragma unroll
    for (int ni = 0; ni < 4; ++ni) {
      int col = coff + nloc + wn * 64 + (ni >> 1) * 32 + (ni & 1) * 16 + lane15;
#pragma unroll
      for (int mi = 0; mi < 8; ++mi) {
        int row = m0 + wm * 128 + (mi >> 2) * 64 + (mi & 3) * 16 + lane4 * 4;
        if (Cb) {
#pragma unroll
          for (int r = 0; r < 4; ++r)
            Cb[(size_t)(row + r) * ldc + col] = f2bf(acc[mi][ni][r]);
        } else {
#pragma unroll
          for (int r = 0; r < 4; ++r)
            Cf[(size_t)(row + r) * ldc + col] = acc[mi][ni][r];
        }
      }
    }
  }
#undef STA
#undef STB
#undef RAF
#undef RBF
#undef MM
#undef BAR
#undef LGKM0
#undef LGKM8
#undef VM6
#undef VM8
}

// ---------- inverse-DFT (+b2, /4) -> 4x LayerNorm -> relu -> forward-DFT -> out bf16 ----------
// NOTE: may be called with h1s == C2 (in-place): each row is fully register-
// resident between read and write (reads all precede the reduction barrier).
__global__ __launch_bounds__(256) void ln_spec_kernel(const unsigned short* C2,
                                                      const float* __restrict__ b2,
                                                      const float* __restrict__ ln_g,
                                                      const float* __restrict__ ln_b,
                                                      unsigned short* h1s) {
  int t = threadIdx.x;
  size_t base = (size_t)blockIdx.x * 8192;
  const ushort4* p = (const ushort4*)(C2 + base);   // planes: v0|v2|vr|vi (512 ushort4 each)
  const float4* bp2 = (const float4*)b2;
  float4 y[4][2];
  float s[4] = {0, 0, 0, 0}, q[4] = {0, 0, 0, 0};
#pragma unroll
  for (int hl = 0; hl < 2; ++hl) {
    int j = hl * 256 + t;
    ushort4 u0 = p[j], u2 = p[512 + j], ur = p[1024 + j], ui = p[1536 + j];
    float4 bb = bp2[j];
#define DO(c)                                                   \
  {                                                             \
    float v0 = bf2f(u0.c), v2 = bf2f(u2.c);                     \
    float vr = bf2f(ur.c), vi = bf2f(ui.c);                     \
    float e0 = 0.25f * (v0 + v2 + 2.f * vr) + bb.c;             \
    float e1 = 0.25f * (v0 - v2 - 2.f * vi) + bb.c;             \
    float e2 = 0.25f * (v0 + v2 - 2.f * vr) + bb.c;             \
    float e3 = 0.25f * (v0 - v2 + 2.f * vi) + bb.c;             \
    y[0][hl].c = e0; y[1][hl].c = e1; y[2][hl].c = e2; y[3][hl].c = e3; \
    s[0] += e0; q[0] += e0 * e0; s[1] += e1; q[1] += e1 * e1;   \
    s[2] += e2; q[2] += e2 * e2; s[3] += e3; q[3] += e3 * e3;   \
  }
    DO(x) DO(y) DO(z) DO(w)
#undef DO
  }
#pragma unroll
  for (int off = 32; off > 0; off >>= 1)
#pragma unroll
    for (int g = 0; g < 4; ++g) {
      s[g] += __shfl_down(s[g], off, 64);
      q[g] += __shfl_down(q[g], off, 64);
    }
  __shared__ float rs[4][4], rq[4][4];
  int w = t >> 6, l = t & 63;
  if (l == 0)
#pragma unroll
    for (int g = 0; g < 4; ++g) { rs[w][g] = s[g]; rq[w][g] = q[g]; }
  __syncthreads();
  float mean[4], rstd[4];
#pragma unroll
  for (int g = 0; g < 4; ++g) {
    float ss = rs[0][g] + rs[1][g] + rs[2][g] + rs[3][g];
    float qq = rq[0][g] + rq[1][g] + rq[2][g] + rq[3][g];
    mean[g] = ss * (1.f / HID);
    float var = qq * (1.f / HID) - mean[g] * mean[g];
    rstd[g] = rsqrtf(var + 1e-5f);
  }
  const float4* gp = (const float4*)ln_g;
  const float4* lbp = (const float4*)ln_b;
#pragma unroll
  for (int hl = 0; hl < 2; ++hl) {
    int j = hl * 256 + t;
    float4 gg = gp[j], lb = lbp[j];
    ushort4 o[4];
#define DO(c)                                                               \
  {                                                                         \
    float h0 = fmaxf((y[0][hl].c - mean[0]) * rstd[0] * gg.c + lb.c, 0.f);  \
    float h1 = fmaxf((y[1][hl].c - mean[1]) * rstd[1] * gg.c + lb.c, 0.f);  \
    float h2 = fmaxf((y[2][hl].c - mean[2]) * rstd[2] * gg.c + lb.c, 0.f);  \
    float h3 = fmaxf((y[3][hl].c - mean[3]) * rstd[3] * gg.c + lb.c, 0.f);  \
    o[0].c = f2bf(h0 + h1 + h2 + h3);                                       \
    o[1].c = f2bf(h0 - h1 + h2 - h3);                                       \
    o[2].c = f2bf(h0 - h2);                                                 \
    o[3].c = f2bf(h3 - h1);                                                 \
  }
    DO(x) DO(y) DO(z) DO(w)
#undef DO
    size_t ob = (size_t)blockIdx.x * 8192;
#pragma unroll
    for (int pl = 0; pl < 4; ++pl)
      ((ushort4*)(h1s + ob + pl * 2048))[j] = o[pl];
  }
}

// ---------- final inverse-DFT (+b3, /4): Z (rows x 2048 f32 [z0|z2|zr|zi]) -> out ----------
__global__ __launch_bounds__(256) void out_ep_kernel(const float* __restrict__ Z,
                                                     const float* __restrict__ b3,
                                                     float* __restrict__ out) {
  int e = blockIdx.x * 256 + threadIdx.x;
  int row = e >> 9, i = e & 511;
  size_t base = (size_t)row * 2048;
  float z0 = Z[base + i], z2 = Z[base + 512 + i];
  float zr = Z[base + 1024 + i], zi = Z[base + 1536 + i];
  float bv = b3[i];
  out[base + i]        = 0.25f * (z0 + z2 + 2.f * zr) + bv;
  out[base + 512 + i]  = 0.25f * (z0 - z2 - 2.f * zi) + bv;
  out[base + 1024 + i] = 0.25f * (z0 + z2 - 2.f * zr) + bv;
  out[base + 1536 + i] = 0.25f * (z0 - z2 + 2.f * zi) + bv;
}

extern "C" void kernel_launch(void* const* d_in, const int* in_sizes, int n_in,
                              void* d_out, int out_size, void* d_ws, size_t ws_size,
                              hipStream_t stream) {
  const float* ins = (const float*)d_in[0];
  const float* w1  = (const float*)d_in[1];
  const float* b1  = (const float*)d_in[2];
  const float* w2  = (const float*)d_in[3];
  const float* b2  = (const float*)d_in[4];
  const float* w3  = (const float*)d_in[5];
  const float* b3  = (const float*)d_in[6];
  const float* lng = (const float*)d_in[7];
  const float* lnb = (const float*)d_in[8];
  float* out = (float*)d_out;
  char* ws = (char*)d_ws;

  // Spectral weights (bf16), persistent at base of ws.
  unsigned short* W0s2 = (unsigned short*)ws;
  unsigned short* W2s2 = W0s2 + 4194304;
  unsigned short* Bc2  = W2s2 + 4194304;
  unsigned short* W0s3 = Bc2 + 16777216;
  unsigned short* W2s3 = W0s3 + 1048576;
  unsigned short* Bc3  = W2s3 + 1048576;
  const size_t WT_BYTES = 62914560ull;
  char* chunk_base = ws + WT_BYTES;

  wtrans_kernel<2048><<<4096, 256, 0, stream>>>(w2, W0s2, W2s2, Bc2);
  wtrans_kernel<512><<<1024, 256, 0, stream>>>(w3, W0s3, W2s3, Bc3);

  const size_t H1F_BYTES = (size_t)MROWS * 8192 * 2;    // 168 MB (full h1s; first half reused as Z f32)
  const size_t H1_BYTES  = (size_t)5120 * 8192 * 2;     // 84 MB (chunked h1s / Z full f32)
  const size_t H2_BYTES  = (size_t)MROWS * 8192 * 2;    // 168 MB
  const size_t need_merged = WT_BYTES + H1F_BYTES + H2_BYTES + 4096;
  const size_t need_full   = WT_BYTES + H1_BYTES + H2_BYTES + 4096;

  if (ws_size >= need_merged) {
    // ---- fully merged path: full-rows L1 -> ONE L2 GEMM (1280 tiles) -> LN -> L3 ----
    unsigned short* h1s = (unsigned short*)chunk_base;                // 10240 x 8192 bf16
    float*          Z   = (float*)chunk_base;                         // 10240 x 2048 f32 (alias; h1s dead by then)
    unsigned short* H2  = (unsigned short*)(chunk_base + H1F_BYTES);  // 10240 x 8192 bf16
    const int MTN = MROWS / 256;  // 40
    layer1_kernel<<<dim3(MROWS / 32, 8), 256, 0, stream>>>(ins, w1, b1, h1s, 0);
    gemm_spec<<<256, 512, 0, stream>>>(h1s, W0s2, W2s2, Bc2, nullptr, H2,
                                       8, 16, 2048, 8192, 32 * MTN, 16 * MTN, MTN);
    ln_spec_kernel<<<MROWS, 256, 0, stream>>>(H2, b2, lng, lnb, H2);
    gemm_spec<<<256, 512, 0, stream>>>(H2, W0s3, W2s3, Bc3, Z, nullptr,
                                       2, 4, 512, 2048, 8 * MTN, 4 * MTN, MTN);
    out_ep_kernel<<<MROWS * 2, 256, 0, stream>>>(Z, b3, out);
  } else if (ws_size >= need_full) {
    // ---- fused-L3 path (R9): 2 chunks for L2; one full-rows L3 ----
    unsigned short* h1s = (unsigned short*)chunk_base;               // 5120 x 8192 bf16
    float*          Z   = (float*)chunk_base;                        // 10240 x 2048 f32 (alias)
    unsigned short* H2  = (unsigned short*)(chunk_base + H1_BYTES);  // 10240 x 8192 bf16
    const int Mc = 5120, MTN = Mc / 256;
    for (int c = 0; c < 2; ++c) {
      int row0 = c * Mc;
      unsigned short* H2c = H2 + (size_t)row0 * 8192;
      layer1_kernel<<<dim3(Mc / 32, 8), 256, 0, stream>>>(ins, w1, b1, h1s, row0);
      gemm_spec<<<256, 512, 0, stream>>>(h1s, W0s2, W2s2, Bc2, nullptr, H2c,
                                         8, 16, 2048, 8192, 32 * MTN, 16 * MTN, MTN);
      ln_spec_kernel<<<Mc, 256, 0, stream>>>(H2c, b2, lng, lnb, H2c);
    }
    {
      const int MT3 = MROWS / 256;
      gemm_spec<<<256, 512, 0, stream>>>(H2, W0s3, W2s3, Bc3, Z, nullptr,
                                         2, 4, 512, 2048, 8 * MT3, 4 * MT3, MT3);
      out_ep_kernel<<<MROWS * 2, 256, 0, stream>>>(Z, b3, out);
    }
  } else {
    // ---- fallback: chunked flow (persistent-snake GEMMs) ----
    static const int Pcand[8] = {1, 2, 4, 5, 8, 10, 20, 40};
    int P = 40;
    for (int pi = 0; pi < 8; ++pi) {
      size_t mc = (size_t)MROWS / Pcand[pi];
      size_t need = WT_BYTES + mc * 8192 * 2 * 2 + 4096;
      if (need <= ws_size) { P = Pcand[pi]; break; }
    }
    const int Mc = MROWS / P, MTN = Mc / 256;
    unsigned short* h1s = (unsigned short*)chunk_base;                     // Mc x 8192 bf16
    unsigned short* C2  = (unsigned short*)(chunk_base + (size_t)Mc * 8192 * 2);
    float*          Z   = (float*)C2;                                      // Mc x 2048 f32 (alias)
    for (int c = 0; c < P; ++c) {
      int row0 = c * Mc;
      layer1_kernel<<<dim3(Mc / 32, 8), 256, 0, stream>>>(ins, w1, b1, h1s, row0);
      gemm_spec<<<256, 512, 0, stream>>>(h1s, W0s2, W2s2, Bc2, nullptr, C2,
                                         8, 16, 2048, 8192, 32 * MTN, 16 * MTN, MTN);
      ln_spec_kernel<<<Mc, 256, 0, stream>>>(C2, b2, lng, lnb, h1s);
      gemm_spec<<<256, 512, 0, stream>>>(h1s, W0s3, W2s3, Bc3, Z, nullptr,
                                         2, 4, 512, 2048, 8 * MTN, 4 * MTN, MTN);
      out_ep_kernel<<<Mc * 2, 256, 0, stream>>>(Z, b3, out + (size_t)row0 * 2048);
    }
  }
}